// Round 12
// baseline (800.288 us; speedup 1.0000x reference)
//
#include <hip/hip_runtime.h>

typedef unsigned int u32;
typedef unsigned short u16;
using bf16x8 = __attribute__((ext_vector_type(8))) short;
using f32x4  = __attribute__((ext_vector_type(4))) float;

static inline int idiv_up(int a, int b) { return (a + b - 1) / b; }

#define BSHIFT 11          // bucket width 2048 nodes
#define BW     2048
#define ACHUNK 8192        // edges per binA block

// ---------------- bf16 pack/unpack ----------------

__device__ __forceinline__ u32 pack_bf16_rne(float lo, float hi) {
    u32 ul = __float_as_uint(lo);
    u32 uh = __float_as_uint(hi);
    ul = (ul + 0x7fffu + ((ul >> 16) & 1u)) >> 16;
    uh = (uh + 0x7fffu + ((uh >> 16) & 1u));
    return (ul & 0xffffu) | (uh & 0xffff0000u);
}
__device__ __forceinline__ u16 bf16_rne1(float v) {
    u32 u = __float_as_uint(v);
    return (u16)((u + 0x7fffu + ((u >> 16) & 1u)) >> 16);
}
__device__ __forceinline__ float bf16_lo(u32 u) { return __uint_as_float(u << 16); }
__device__ __forceinline__ float bf16_hi(u32 u) { return __uint_as_float(u & 0xffff0000u); }

// ---------------- fused: count_deg (int4) ∥ wprep ∥ combined-bias ----------------

__global__ __launch_bounds__(256) void prep_kernel(
    const int* __restrict__ colL, const int* __restrict__ colN,
    int eL, int eN,
    int* __restrict__ degL, int* __restrict__ degN,
    const float* __restrict__ W1L, const float* __restrict__ W1N,
    const float* __restrict__ W2L, const float* __restrict__ W2N,
    u16* __restrict__ T1L, u16* __restrict__ T1N,
    u16* __restrict__ T2L, u16* __restrict__ T2N,
    const float* __restrict__ b1L, const float* __restrict__ b1N,
    const float* __restrict__ b2L, const float* __restrict__ b2N,
    float* __restrict__ cb1, float* __restrict__ cb2,
    int nCount)
{
    const int t = threadIdx.x;
    if ((int)blockIdx.x < nCount) {
        int i4 = blockIdx.x * 256 + t;
        if (i4 < (eL >> 2)) {
            int4 c = ((const int4*)colL)[i4];
            atomicAdd(&degL[c.x], 1); atomicAdd(&degL[c.y], 1);
            atomicAdd(&degL[c.z], 1); atomicAdd(&degL[c.w], 1);
        }
        if (i4 < (eN >> 2)) {
            int4 c = ((const int4*)colN)[i4];
            atomicAdd(&degN[c.x], 1); atomicAdd(&degN[c.y], 1);
            atomicAdd(&degN[c.z], 1); atomicAdd(&degN[c.w], 1);
        }
        if (blockIdx.x == 0) {
            if (t < (eL & 3)) atomicAdd(&degL[colL[(eL & ~3) + t]], 1);
            if (t < (eN & 3)) atomicAdd(&degN[colN[(eN & ~3) + t]], 1);
        }
    } else if ((int)blockIdx.x < nCount + 256) {
        int b = blockIdx.x - nCount;          // 0..255
        int which = b >> 6, bx = b & 63;
        const float* src = which == 0 ? W1L : which == 1 ? W1N : which == 2 ? W2L : W2N;
        u16* dst         = which == 0 ? T1L : which == 1 ? T1N : which == 2 ? T2L : T2N;
        const int nc = which < 2 ? 128 : 64;
        int i = bx * 256 + t;
        if (i < 128 * nc) {
            int k = i / nc, nn = i % nc;
            dst[nn * 128 + k] = bf16_rne1(src[i]);
        }
    } else {
        if (t < 128) cb1[t] = b1L[t] + 0.5f * b1N[t];
        if (t < 64)  cb2[t] = b2L[t] + 0.5f * b2N[t];
    }
}

// ---------------- fused: scan(+gcur emission) ∥ dinv ----------------

__global__ __launch_bounds__(1024) void scan_dinv_kernel(
    const int* __restrict__ degL, const int* __restrict__ degN, int n,
    int* __restrict__ rowptrL, int* __restrict__ rowptrN,
    int* __restrict__ gcurL, int* __restrict__ gcurN,
    float* __restrict__ dinvL, float* __restrict__ dinvN)
{
    const int t = threadIdx.x;
    if (blockIdx.x < 2) {
        const int* deg = blockIdx.x ? degN : degL;
        int* rowptr    = blockIdx.x ? rowptrN : rowptrL;
        int* gcur      = blockIdx.x ? gcurN : gcurL;

        __shared__ int ls[1024];
        const int chunk = (n + 1023) / 1024;
        const int base = t * chunk;

        int s = 0;
        for (int i = 0; i < chunk; ++i) {
            int idx = base + i;
            if (idx < n) s += deg[idx];
        }
        ls[t] = s;
        __syncthreads();
        for (int off = 1; off < 1024; off <<= 1) {
            int add = (t >= off) ? ls[t - off] : 0;
            __syncthreads();
            ls[t] += add;
            __syncthreads();
        }
        int running = (t == 0) ? 0 : ls[t - 1];
        int total = ls[1023];
        for (int i = 0; i < chunk; ++i) {
            int idx = base + i;
            if (idx < n) {
                rowptr[idx] = running;
                if ((idx & (BW - 1)) == 0) gcur[idx >> BSHIFT] = running;
                running += deg[idx];
            }
        }
        if (t == 1023) rowptr[n] = total;
    } else {
        int i = (blockIdx.x - 2) * 1024 + t;
        if (i < n) {
            dinvL[i] = rsqrtf((float)degL[i] + 1.0f);   // +1 self loop
            dinvN[i] = rsqrtf((float)degN[i] + 1.0f);
        }
    }
}

// ---------------- fused: binA ∥ x->bf16 quant ----------------

__global__ __launch_bounds__(256) void binA_xq_kernel(
    const int* __restrict__ rowL, const int* __restrict__ colL, int eL,
    const int* __restrict__ rowN, const int* __restrict__ colN, int eN,
    int* __restrict__ gcurL, int* __restrict__ gcurN,
    uint2* __restrict__ stagedL, uint2* __restrict__ stagedN, int nb, int nA,
    const float* __restrict__ x, u32* __restrict__ xb, int nx4)
{
    const int t = threadIdx.x;
    if ((int)blockIdx.x < 2 * nA) {
        const int adj = (int)blockIdx.x >= nA;
        const int chunkb = adj ? blockIdx.x - nA : blockIdx.x;
        const int* rowA = adj ? rowN : rowL;
        const int* colA = adj ? colN : colL;
        const int e     = adj ? eN   : eL;
        int* gcur       = adj ? gcurN : gcurL;
        uint2* staged   = adj ? stagedN : stagedL;

        __shared__ int hist[64];
        __shared__ int base[64];
        if (t < 64) hist[t] = 0;
        __syncthreads();

        const int i0 = chunkb * ACHUNK;
        const int i1 = min(i0 + ACHUNK, e);

        for (int i = i0 + t; i < i1; i += 256)
            atomicAdd(&hist[colA[i] >> BSHIFT], 1);
        __syncthreads();

        if (t < 64) {
            int cnt = hist[t];
            if (t < nb && cnt > 0) base[t] = atomicAdd(&gcur[t], cnt);
        }
        __syncthreads();
        if (t < 64) hist[t] = 0;
        __syncthreads();

        for (int i = i0 + t; i < i1; i += 256) {
            int c = colA[i], r = rowA[i];
            int b = c >> BSHIFT;
            int pos = base[b] + atomicAdd(&hist[b], 1);
            staged[pos] = make_uint2((u32)c, (u32)r);
        }
    } else {
        int i4 = ((int)blockIdx.x - 2 * nA) * 256 + t;
        if (i4 < nx4) {
            float4 v = ((const float4*)x)[i4];
            ((uint2*)xb)[i4] = make_uint2(pack_bf16_rne(v.x, v.y),
                                          pack_bf16_rne(v.z, v.w));
        }
    }
}

// ---------------- radix pass B ----------------

__global__ __launch_bounds__(256) void binB_kernel(
    const int* __restrict__ rowptrL, const int* __restrict__ rowptrN,
    const uint2* __restrict__ stagedL, const uint2* __restrict__ stagedN,
    int* __restrict__ csrL, int* __restrict__ csrN, int n)
{
    const int adj = blockIdx.y;
    const int* rowptr   = adj ? rowptrN : rowptrL;
    const uint2* staged = adj ? stagedN : stagedL;
    int* csr            = adj ? csrN    : csrL;

    __shared__ int lcur[BW];
    const int lo = blockIdx.x << BSHIFT;
    const int hi = min(lo + BW, n);
    const int t = threadIdx.x;

    for (int i = lo + t; i < hi; i += 256) lcur[i - lo] = rowptr[i];
    __syncthreads();

    const int s0 = rowptr[lo], s1 = rowptr[hi];
    for (int i = s0 + t; i < s1; i += 256) {
        uint2 er = staged[i];
        int p = atomicAdd(&lcur[(int)er.x - lo], 1);
        csr[p] = (int)er.y;
    }
}

// ---------------- gatherx: agg{L,N}[v] = sum src[u]*dinv[u] + self ----------
// Single shared source table (bf16, [n][128] = 64 u32/row) serves BOTH
// adjacency streams -> random working set 25.6 MB (half of before).
// Dual-stream 8-deep pipelined; per-source dinv applied as broadcast scale
// (tail mask folded into the scale).

__global__ __launch_bounds__(256) void gatherx_kernel(
    const int* __restrict__ rowptrL, const int* __restrict__ csrL,
    const int* __restrict__ rowptrN, const int* __restrict__ csrN,
    const u32* __restrict__ src,
    const float* __restrict__ dinvL, const float* __restrict__ dinvN,
    u32* __restrict__ aggL, u32* __restrict__ aggN, int n)
{
    const int c  = threadIdx.x & 63;
    const int wv = threadIdx.x >> 6;

    for (int node = blockIdx.x * 4 + wv; node < n; node += gridDim.x * 4) {
        u32 xv = src[(size_t)node * 64 + c];
        float dlv = dinvL[node], dnv = dinvN[node];
        float sL0 = dlv * bf16_lo(xv), sL1 = dlv * bf16_hi(xv);
        float sN0 = dnv * bf16_lo(xv), sN1 = dnv * bf16_hi(xv);

        int jL  = __builtin_amdgcn_readfirstlane(rowptrL[node]);
        int e2L = __builtin_amdgcn_readfirstlane(rowptrL[node + 1]);
        int jN  = __builtin_amdgcn_readfirstlane(rowptrN[node]);
        int e2N = __builtin_amdgcn_readfirstlane(rowptrN[node + 1]);
        const int lenL = e2L - jL;
        const int lenN = e2N - jN;

        int idxL[8], idxN[8];
        if (lenL > 0) {
            #pragma unroll
            for (int k = 0; k < 8; ++k) idxL[k] = csrL[jL + min(k, lenL - 1)];
        }
        if (lenN > 0) {
            #pragma unroll
            for (int k = 0; k < 8; ++k) idxN[k] = csrN[jN + min(k, lenN - 1)];
        }

        const int mx = max(lenL, lenN);
        for (int base = 0; base < mx; base += 8) {
            const bool doL = base < lenL;
            const bool doN = base < lenN;
            u32 aL[8], aN[8];
            float dl[8], dn[8];
            if (doL) {
                #pragma unroll
                for (int k = 0; k < 8; ++k) aL[k] = src[(size_t)idxL[k] * 64 + c];
                #pragma unroll
                for (int k = 0; k < 8; ++k) {
                    float d = dinvL[idxL[k]];
                    dl[k] = (base + k < lenL) ? d : 0.f;
                }
            }
            if (doN) {
                #pragma unroll
                for (int k = 0; k < 8; ++k) aN[k] = src[(size_t)idxN[k] * 64 + c];
                #pragma unroll
                for (int k = 0; k < 8; ++k) {
                    float d = dinvN[idxN[k]];
                    dn[k] = (base + k < lenN) ? d : 0.f;
                }
            }
            if (doL && base + 8 < lenL) {
                #pragma unroll
                for (int k = 0; k < 8; ++k) idxL[k] = csrL[jL + min(base + 8 + k, lenL - 1)];
            }
            if (doN && base + 8 < lenN) {
                #pragma unroll
                for (int k = 0; k < 8; ++k) idxN[k] = csrN[jN + min(base + 8 + k, lenN - 1)];
            }
            if (doL) {
                #pragma unroll
                for (int k = 0; k < 8; ++k) {
                    sL0 = fmaf(dl[k], bf16_lo(aL[k]), sL0);
                    sL1 = fmaf(dl[k], bf16_hi(aL[k]), sL1);
                }
            }
            if (doN) {
                #pragma unroll
                for (int k = 0; k < 8; ++k) {
                    sN0 = fmaf(dn[k], bf16_lo(aN[k]), sN0);
                    sN1 = fmaf(dn[k], bf16_hi(aN[k]), sN1);
                }
            }
        }

        aggL[(size_t)node * 64 + c] = pack_bf16_rne(sL0, sL1);
        aggN[(size_t)node * 64 + c] = pack_bf16_rne(sN0, sN1);
    }
}

// ---------------- combine GEMM: out = dinvL⊙(aggL@WL) + 0.5·dinvN⊙(aggN@WN) + cb
// agg tables bf16 [n][128]; Wt bf16 [NCH][128] (pre-transposed). Wt = MFMA
// A-operand, agg = B-operand -> lane holds 4 consecutive out-channels of one
// node; L/N partials combined in-register. STATS: BN sum/sumsq in epilogue,
// output packed bf16 h. !STATS: fp32 output.

template<int NCH, bool STATS>
__global__ __launch_bounds__(256) void combine_gemm_kernel(
    const u32* __restrict__ aggL, const u32* __restrict__ aggN, int n,
    const u16* __restrict__ WtL, const u16* __restrict__ WtN,
    const float* __restrict__ dinvL, const float* __restrict__ dinvN,
    const float* __restrict__ cb,
    void* __restrict__ outp,
    float* __restrict__ bn_sum, float* __restrict__ bn_sumsq)
{
    constexpr int CT = NCH / 64;       // ch-tiles per wave: 128->2, 64->1
    __shared__ u16 ls[2][64 * 128];
    __shared__ float bns[128], bnq[128];

    const int t = threadIdx.x;
    const int row0 = blockIdx.x * 64;
    if (STATS && t < 128) { bns[t] = 0.f; bnq[t] = 0.f; }

    const uint4* gL = (const uint4*)aggL;
    const uint4* gN = (const uint4*)aggN;
    #pragma unroll
    for (int i = 0; i < 8; ++i) {
        int flat = i * 256 + t;            // 0..2047
        int table = flat >> 10;
        int q = flat & 1023;
        int r = q >> 4, c16 = q & 15;
        int rr = row0 + r;
        uint4 v = make_uint4(0, 0, 0, 0);
        const uint4* g = table ? gN : gL;
        if (rr < n) v = g[(size_t)rr * 16 + c16];
        int byte = (r * 256 + c16 * 16) ^ ((r & 7) << 4);
        *(uint4*)((char*)(&ls[table][0]) + byte) = v;
    }
    __syncthreads();

    const int l = t & 63, w = t >> 6;
    const int lm = l & 15, lq = l >> 4;
    const int chbase = w * (NCH / 4);

    f32x4 accL[CT][4], accN[CT][4];
    #pragma unroll
    for (int ct = 0; ct < CT; ++ct)
        #pragma unroll
        for (int nt = 0; nt < 4; ++nt) {
            accL[ct][nt] = (f32x4){0.f, 0.f, 0.f, 0.f};
            accN[ct][nt] = (f32x4){0.f, 0.f, 0.f, 0.f};
        }

    #pragma unroll
    for (int ks = 0; ks < 4; ++ks) {
        const int k0 = ks * 32 + lq * 8;
        bf16x8 wfL[CT], wfN[CT];
        #pragma unroll
        for (int ct = 0; ct < CT; ++ct) {
            int ch = chbase + ct * 16 + lm;
            wfL[ct] = *(const bf16x8*)&WtL[(size_t)ch * 128 + k0];
            wfN[ct] = *(const bf16x8*)&WtN[(size_t)ch * 128 + k0];
        }
        #pragma unroll
        for (int nt = 0; nt < 4; ++nt) {
            int m = nt * 16 + lm;
            int byte = (m * 256 + k0 * 2) ^ ((m & 7) << 4);
            bf16x8 xL = *(const bf16x8*)((const char*)(&ls[0][0]) + byte);
            bf16x8 xN = *(const bf16x8*)((const char*)(&ls[1][0]) + byte);
            #pragma unroll
            for (int ct = 0; ct < CT; ++ct) {
                accL[ct][nt] = __builtin_amdgcn_mfma_f32_16x16x32_bf16(
                    wfL[ct], xL, accL[ct][nt], 0, 0, 0);
                accN[ct][nt] = __builtin_amdgcn_mfma_f32_16x16x32_bf16(
                    wfN[ct], xN, accN[ct][nt], 0, 0, 0);
            }
        }
    }

    float sv[CT][4], sq[CT][4];
    #pragma unroll
    for (int ct = 0; ct < CT; ++ct)
        #pragma unroll
        for (int r = 0; r < 4; ++r) { sv[ct][r] = 0.f; sq[ct][r] = 0.f; }

    #pragma unroll
    for (int nt = 0; nt < 4; ++nt) {
        int node = row0 + nt * 16 + lm;
        bool ok = node < n;
        int nodec = ok ? node : 0;
        float dl = ok ? dinvL[nodec] : 0.f;
        float dn = ok ? 0.5f * dinvN[nodec] : 0.f;
        #pragma unroll
        for (int ct = 0; ct < CT; ++ct) {
            int ch0 = chbase + ct * 16 + lq * 4;
            float4 cbv = *(const float4*)&cb[ch0];
            f32x4 aL = accL[ct][nt], aN = accN[ct][nt];
            float v0 = dl * aL[0] + dn * aN[0] + cbv.x;
            float v1 = dl * aL[1] + dn * aN[1] + cbv.y;
            float v2 = dl * aL[2] + dn * aN[2] + cbv.z;
            float v3 = dl * aL[3] + dn * aN[3] + cbv.w;
            if constexpr (STATS) {
                if (ok) {
                    uint2 pk;
                    pk.x = pack_bf16_rne(v0, v1);
                    pk.y = pack_bf16_rne(v2, v3);
                    *(uint2*)&((u32*)outp)[(size_t)node * 64 + (ch0 >> 1)] = pk;
                    sv[ct][0] += v0; sv[ct][1] += v1; sv[ct][2] += v2; sv[ct][3] += v3;
                    sq[ct][0] += v0 * v0; sq[ct][1] += v1 * v1;
                    sq[ct][2] += v2 * v2; sq[ct][3] += v3 * v3;
                }
            } else {
                if (ok)
                    *(float4*)&((float*)outp)[(size_t)node * NCH + ch0] =
                        make_float4(v0, v1, v2, v3);
            }
        }
    }

    if constexpr (STATS) {
        #pragma unroll
        for (int ct = 0; ct < CT; ++ct)
            #pragma unroll
            for (int r = 0; r < 4; ++r) {
                float a = sv[ct][r], b = sq[ct][r];
                #pragma unroll
                for (int m = 1; m <= 8; m <<= 1) {
                    a += __shfl_xor(a, m, 64);
                    b += __shfl_xor(b, m, 64);
                }
                if (lm == 0) {
                    int ch = chbase + ct * 16 + lq * 4 + r;   // unique per writer
                    bns[ch] = a; bnq[ch] = b;
                }
            }
        __syncthreads();
        if (t < 128) {
            atomicAdd(&bn_sum[t], bns[t]);
            atomicAdd(&bn_sumsq[t], bnq[t]);
        }
    }
}

// ---------------- BN finalize + ReLU + bf16 quant: h -> hb ----------------

__global__ __launch_bounds__(256) void bnquant_kernel(
    const u32* __restrict__ h, u32* __restrict__ hb,
    const float* __restrict__ bn_sum, const float* __restrict__ bn_sumsq,
    const float* __restrict__ gamma, const float* __restrict__ beta,
    float inv_n, int total)                     // total = n*64 u32s
{
    __shared__ float sc_s[128], sh_s[128];
    const int t = threadIdx.x;
    if (t < 128) {
        float mean = bn_sum[t] * inv_n;
        float var  = bn_sumsq[t] * inv_n - mean * mean;
        float sc = gamma[t] * rsqrtf(var + 1e-5f);
        sc_s[t] = sc;
        sh_s[t] = beta[t] - mean * sc;
    }
    __syncthreads();

    int i0 = (blockIdx.x * 256 + t) * 4;
    if (i0 + 4 <= total) {
        uint4 v = *(const uint4*)&h[i0];
        u32 r[4];
        u32 vv[4] = {v.x, v.y, v.z, v.w};
        #pragma unroll
        for (int j = 0; j < 4; ++j) {
            int cp = (i0 + j) & 63;
            float a = fmaxf(bf16_lo(vv[j]) * sc_s[2 * cp]     + sh_s[2 * cp],     0.f);
            float b = fmaxf(bf16_hi(vv[j]) * sc_s[2 * cp + 1] + sh_s[2 * cp + 1], 0.f);
            r[j] = pack_bf16_rne(a, b);
        }
        *(uint4*)&hb[i0] = make_uint4(r[0], r[1], r[2], r[3]);
    } else {
        for (int i = i0; i < total; ++i) {
            int cp = i & 63;
            u32 u = h[i];
            float a = fmaxf(bf16_lo(u) * sc_s[2 * cp]     + sh_s[2 * cp],     0.f);
            float b = fmaxf(bf16_hi(u) * sc_s[2 * cp + 1] + sh_s[2 * cp + 1], 0.f);
            hb[i] = pack_bf16_rne(a, b);
        }
    }
}

// ---------------- launch ----------------

extern "C" void kernel_launch(void* const* d_in, const int* in_sizes, int n_in,
                              void* d_out, int out_size, void* d_ws, size_t ws_size,
                              hipStream_t stream)
{
    const float* x     = (const float*)d_in[0];
    const int*   adjL  = (const int*)d_in[1];   // adj_low
    const int*   adjN  = (const int*)d_in[3];   // adj_nd_low
    const float* W1L   = (const float*)d_in[5];
    const float* b1L   = (const float*)d_in[6];
    const float* W1N   = (const float*)d_in[7];
    const float* b1N   = (const float*)d_in[8];
    const float* gamma = (const float*)d_in[9];
    const float* beta  = (const float*)d_in[10];
    const float* W2L   = (const float*)d_in[11];
    const float* b2L   = (const float*)d_in[12];
    const float* W2N   = (const float*)d_in[13];
    const float* b2N   = (const float*)d_in[14];

    const int n  = in_sizes[0] / 128;
    const int eL = in_sizes[1] / 2;
    const int eN = in_sizes[3] / 2;
    const int* rowL = adjL;  const int* colL = adjL + eL;
    const int* rowN = adjN;  const int* colN = adjN + eN;
    const int nb = idiv_up(n, BW);

    char* p = (char*)d_ws;
    const size_t tb = (size_t)n * 128 * sizeof(u16);    // bf16 [n][128] table
    u32* xb   = (u32*)p; p += tb;       // x bf16; later aliased by hb
    u32* aggL = (u32*)p; p += tb;       // layer agg tables (reused both layers)
    u32* aggN = (u32*)p; p += tb;
    u32* h    = (u32*)p; p += tb;       // h bf16; earlier aliased by staged
    float* dinvL = (float*)p; p += (size_t)n * sizeof(float);
    float* dinvN = (float*)p; p += (size_t)n * sizeof(float);
    float* bn_sum   = (float*)p; p += 128 * sizeof(float);
    float* bn_sumsq = (float*)p; p += 128 * sizeof(float);
    float* cb1 = (float*)p; p += 128 * sizeof(float);
    float* cb2 = (float*)p; p += 64 * sizeof(float);
    int* degL    = (int*)p; p += (size_t)n * sizeof(int);
    int* degN    = (int*)p; p += (size_t)n * sizeof(int);
    int* rowptrL = (int*)p; p += (size_t)(n + 1) * sizeof(int);
    int* rowptrN = (int*)p; p += (size_t)(n + 1) * sizeof(int);
    int* gcurL   = (int*)p; p += 64 * sizeof(int);
    int* gcurN   = (int*)p; p += 64 * sizeof(int);
    int* csrL    = (int*)p; p += (size_t)eL * sizeof(int);
    int* csrN    = (int*)p; p += (size_t)eN * sizeof(int);
    u16* WtL1 = (u16*)p; p += 128 * 128 * sizeof(u16);
    u16* WtN1 = (u16*)p; p += 128 * 128 * sizeof(u16);
    u16* WtL2 = (u16*)p; p += 64 * 128 * sizeof(u16);
    u16* WtN2 = (u16*)p; p += 64 * 128 * sizeof(u16);

    // staged (eL+eN uint2 = 25.6 MB) aliases h (25.6 MB): staged dead after
    // binB; h written first by combine_gemm<128> (after binB). Stream-ordered.
    uint2* stagedL = (uint2*)h;
    uint2* stagedN = stagedL + eL;
    // hb aliases xb: xb dead after first gatherx; hb written by bnquant later.
    u32* hb = xb;

    hipMemsetAsync(degL, 0, (size_t)n * 2 * sizeof(int), stream);
    hipMemsetAsync(bn_sum, 0, 2 * 128 * sizeof(float), stream);

    const int emax = eL > eN ? eL : eN;

    // 1. count_deg ∥ wprep ∥ combined-bias
    const int nCount = idiv_up(emax >> 2, 256);
    prep_kernel<<<nCount + 256 + 1, 256, 0, stream>>>(
        colL, colN, eL, eN, degL, degN,
        W1L, W1N, W2L, W2N, WtL1, WtN1, WtL2, WtN2,
        b1L, b1N, b2L, b2N, cb1, cb2, nCount);

    // 2. scan (+gcur) ∥ dinv
    scan_dinv_kernel<<<2 + idiv_up(n, 1024), 1024, 0, stream>>>(
        degL, degN, n, rowptrL, rowptrN, gcurL, gcurN, dinvL, dinvN);

    // 3. binA ∥ x->bf16
    const int nA = idiv_up(emax, ACHUNK);
    const int nx4 = n * 32;
    binA_xq_kernel<<<2 * nA + idiv_up(nx4, 256), 256, 0, stream>>>(
        rowL, colL, eL, rowN, colN, eN, gcurL, gcurN, stagedL, stagedN, nb, nA,
        x, xb, nx4);

    // 4. binB
    binB_kernel<<<dim3(nb, 2), 256, 0, stream>>>(
        rowptrL, rowptrN, stagedL, stagedN, csrL, csrN, n);

    // 5. layer-1 gather in x-space (single 25.6 MB table)
    gatherx_kernel<<<4096, 256, 0, stream>>>(
        rowptrL, csrL, rowptrN, csrN, xb, dinvL, dinvN, aggL, aggN, n);

    // 6. layer-1 combine GEMM (+BN stats) -> h bf16
    combine_gemm_kernel<128, true><<<idiv_up(n, 64), 256, 0, stream>>>(
        aggL, aggN, n, WtL1, WtN1, dinvL, dinvN, cb1, h, bn_sum, bn_sumsq);

    // 7. BN finalize + ReLU + quant -> hb
    bnquant_kernel<<<idiv_up(n * 64, 1024), 256, 0, stream>>>(
        h, hb, bn_sum, bn_sumsq, gamma, beta, 1.0f / (float)n, n * 64);

    // 8. layer-2 gather in h-space (single 25.6 MB table)
    gatherx_kernel<<<4096, 256, 0, stream>>>(
        rowptrL, csrL, rowptrN, csrN, hb, dinvL, dinvN, aggL, aggN, n);

    // 9. layer-2 combine GEMM -> d_out fp32
    combine_gemm_kernel<64, false><<<idiv_up(n, 64), 256, 0, stream>>>(
        aggL, aggN, n, WtL2, WtN2, dinvL, dinvN, cb2, d_out, nullptr, nullptr);
}

// Round 13
// 621.099 us; speedup vs baseline: 1.2885x; 1.2885x over previous
//
#include <hip/hip_runtime.h>

typedef unsigned int u32;
typedef unsigned short u16;
using bf16x8 = __attribute__((ext_vector_type(8))) short;
using f32x4  = __attribute__((ext_vector_type(4))) float;

static inline int idiv_up(int a, int b) { return (a + b - 1) / b; }

#define BSHIFT 11          // bucket width 2048 nodes
#define BW     2048
#define STILE  2048        // scan tile == BW so gcur[b] = tile offset
#define ACHUNK 8192        // edges per binA block

// ---------------- bf16 pack/unpack ----------------

__device__ __forceinline__ u32 pack_bf16_rne(float lo, float hi) {
    u32 ul = __float_as_uint(lo);
    u32 uh = __float_as_uint(hi);
    ul = (ul + 0x7fffu + ((ul >> 16) & 1u)) >> 16;
    uh = (uh + 0x7fffu + ((uh >> 16) & 1u));
    return (ul & 0xffffu) | (uh & 0xffff0000u);
}
__device__ __forceinline__ u16 bf16_rne1(float v) {
    u32 u = __float_as_uint(v);
    return (u16)((u + 0x7fffu + ((u >> 16) & 1u)) >> 16);
}
__device__ __forceinline__ float bf16_lo(u32 u) { return __uint_as_float(u << 16); }
__device__ __forceinline__ float bf16_hi(u32 u) { return __uint_as_float(u & 0xffff0000u); }

// ---------------- fused: count_deg (int4) ∥ wprep ∥ combined-bias ----------------

__global__ __launch_bounds__(256) void prep_kernel(
    const int* __restrict__ colL, const int* __restrict__ colN,
    int eL, int eN,
    int* __restrict__ degL, int* __restrict__ degN,
    const float* __restrict__ W1L, const float* __restrict__ W1N,
    const float* __restrict__ W2L, const float* __restrict__ W2N,
    u16* __restrict__ T1L, u16* __restrict__ T1N,
    u16* __restrict__ T2L, u16* __restrict__ T2N,
    const float* __restrict__ b1L, const float* __restrict__ b1N,
    const float* __restrict__ b2L, const float* __restrict__ b2N,
    float* __restrict__ cb1, float* __restrict__ cb2,
    int nCount)
{
    const int t = threadIdx.x;
    if ((int)blockIdx.x < nCount) {
        int i4 = blockIdx.x * 256 + t;
        if (i4 < (eL >> 2)) {
            int4 c = ((const int4*)colL)[i4];
            atomicAdd(&degL[c.x], 1); atomicAdd(&degL[c.y], 1);
            atomicAdd(&degL[c.z], 1); atomicAdd(&degL[c.w], 1);
        }
        if (i4 < (eN >> 2)) {
            int4 c = ((const int4*)colN)[i4];
            atomicAdd(&degN[c.x], 1); atomicAdd(&degN[c.y], 1);
            atomicAdd(&degN[c.z], 1); atomicAdd(&degN[c.w], 1);
        }
        if (blockIdx.x == 0) {
            if (t < (eL & 3)) atomicAdd(&degL[colL[(eL & ~3) + t]], 1);
            if (t < (eN & 3)) atomicAdd(&degN[colN[(eN & ~3) + t]], 1);
        }
    } else if ((int)blockIdx.x < nCount + 256) {
        int b = blockIdx.x - nCount;          // 0..255
        int which = b >> 6, bx = b & 63;
        const float* src = which == 0 ? W1L : which == 1 ? W1N : which == 2 ? W2L : W2N;
        u16* dst         = which == 0 ? T1L : which == 1 ? T1N : which == 2 ? T2L : T2N;
        const int nc = which < 2 ? 128 : 64;
        int i = bx * 256 + t;
        if (i < 128 * nc) {
            int k = i / nc, nn = i % nc;
            dst[nn * 128 + k] = bf16_rne1(src[i]);
        }
    } else {
        if (t < 128) cb1[t] = b1L[t] + 0.5f * b1N[t];
        if (t < 64)  cb2[t] = b2L[t] + 0.5f * b2N[t];
    }
}

// ---------------- parallel scan, phase A: per-tile sums ----------------

__global__ __launch_bounds__(256) void scanA_kernel(
    const int* __restrict__ degL, const int* __restrict__ degN, int n,
    int* __restrict__ psum)
{
    const int adj = blockIdx.y;
    const int* deg = adj ? degN : degL;
    const int t = threadIdx.x;
    const int base = blockIdx.x * STILE + t * 8;
    int s = 0;
    #pragma unroll
    for (int j = 0; j < 8; ++j) {
        int idx = base + j;
        if (idx < n) s += deg[idx];
    }
    __shared__ int ls[256];
    ls[t] = s;
    __syncthreads();
    for (int off = 128; off > 0; off >>= 1) {
        if (t < off) ls[t] += ls[t + off];
        __syncthreads();
    }
    if (t == 0) psum[adj * 64 + blockIdx.x] = ls[0];
}

// ---------------- phase B: wave-scan partials -> tile offsets, gcur, rowptr[n]

__global__ __launch_bounds__(64) void scanB_kernel(
    int* __restrict__ psum, int nt,
    int* __restrict__ rowptrL, int* __restrict__ rowptrN,
    int* __restrict__ gcurL, int* __restrict__ gcurN, int n)
{
    const int l = threadIdx.x;   // 64 lanes; nt <= 64
    #pragma unroll
    for (int adj = 0; adj < 2; ++adj) {
        int v = (l < nt) ? psum[adj * 64 + l] : 0;
        int orig = v;
        for (int off = 1; off < 64; off <<= 1) {
            int u = __shfl_up(v, off, 64);
            if (l >= off) v += u;
        }
        int excl = v - orig;
        if (l < nt) {
            psum[adj * 64 + l] = excl;
            int* gcur = adj ? gcurN : gcurL;
            gcur[l] = excl;                 // rowptr[l*BW] == tile offset
        }
        if (l == 63) {
            int* rowptr = adj ? rowptrN : rowptrL;
            rowptr[n] = v;                  // grand total
        }
    }
}

// ---------------- phase C: per-tile exclusive rescan -> rowptr (+dinv fused)

__global__ __launch_bounds__(256) void scanC_kernel(
    const int* __restrict__ degL, const int* __restrict__ degN, int n,
    const int* __restrict__ psum,
    int* __restrict__ rowptrL, int* __restrict__ rowptrN,
    float* __restrict__ dinvL, float* __restrict__ dinvN)
{
    const int adj = blockIdx.y;
    const int* deg = adj ? degN : degL;
    int* rowptr    = adj ? rowptrN : rowptrL;
    float* dinv    = adj ? dinvN : dinvL;
    const int t = threadIdx.x;
    const int base = blockIdx.x * STILE + t * 8;

    int d[8]; int s = 0;
    #pragma unroll
    for (int j = 0; j < 8; ++j) {
        int idx = base + j;
        d[j] = (idx < n) ? deg[idx] : 0;
        s += d[j];
    }
    __shared__ int ls[256];
    ls[t] = s;
    __syncthreads();
    for (int off = 1; off < 256; off <<= 1) {
        int a = (t >= off) ? ls[t - off] : 0;
        __syncthreads();
        ls[t] += a;
        __syncthreads();
    }
    int running = psum[adj * 64 + blockIdx.x] + ls[t] - s;   // exclusive
    #pragma unroll
    for (int j = 0; j < 8; ++j) {
        int idx = base + j;
        if (idx < n) {
            rowptr[idx] = running;
            running += d[j];
            dinv[idx] = rsqrtf((float)d[j] + 1.0f);   // +1 self loop
        }
    }
}

// ---------------- fused: binA ∥ x->bf16 quant ----------------

__global__ __launch_bounds__(256) void binA_xq_kernel(
    const int* __restrict__ rowL, const int* __restrict__ colL, int eL,
    const int* __restrict__ rowN, const int* __restrict__ colN, int eN,
    int* __restrict__ gcurL, int* __restrict__ gcurN,
    uint2* __restrict__ stagedL, uint2* __restrict__ stagedN, int nb, int nA,
    const float* __restrict__ x, u32* __restrict__ xb, int nx4)
{
    const int t = threadIdx.x;
    if ((int)blockIdx.x < 2 * nA) {
        const int adj = (int)blockIdx.x >= nA;
        const int chunkb = adj ? blockIdx.x - nA : blockIdx.x;
        const int* rowA = adj ? rowN : rowL;
        const int* colA = adj ? colN : colL;
        const int e     = adj ? eN   : eL;
        int* gcur       = adj ? gcurN : gcurL;
        uint2* staged   = adj ? stagedN : stagedL;

        __shared__ int hist[64];
        __shared__ int base[64];
        if (t < 64) hist[t] = 0;
        __syncthreads();

        const int i0 = chunkb * ACHUNK;
        const int i1 = min(i0 + ACHUNK, e);

        for (int i = i0 + t; i < i1; i += 256)
            atomicAdd(&hist[colA[i] >> BSHIFT], 1);
        __syncthreads();

        if (t < 64) {
            int cnt = hist[t];
            if (t < nb && cnt > 0) base[t] = atomicAdd(&gcur[t], cnt);
        }
        __syncthreads();
        if (t < 64) hist[t] = 0;
        __syncthreads();

        for (int i = i0 + t; i < i1; i += 256) {
            int c = colA[i], r = rowA[i];
            int b = c >> BSHIFT;
            int pos = base[b] + atomicAdd(&hist[b], 1);
            staged[pos] = make_uint2((u32)c, (u32)r);
        }
    } else {
        int i4 = ((int)blockIdx.x - 2 * nA) * 256 + t;
        if (i4 < nx4) {
            float4 v = ((const float4*)x)[i4];
            ((uint2*)xb)[i4] = make_uint2(pack_bf16_rne(v.x, v.y),
                                          pack_bf16_rne(v.z, v.w));
        }
    }
}

// ---------------- radix pass B ----------------

__global__ __launch_bounds__(256) void binB_kernel(
    const int* __restrict__ rowptrL, const int* __restrict__ rowptrN,
    const uint2* __restrict__ stagedL, const uint2* __restrict__ stagedN,
    int* __restrict__ csrL, int* __restrict__ csrN, int n)
{
    const int adj = blockIdx.y;
    const int* rowptr   = adj ? rowptrN : rowptrL;
    const uint2* staged = adj ? stagedN : stagedL;
    int* csr            = adj ? csrN    : csrL;

    __shared__ int lcur[BW];
    const int lo = blockIdx.x << BSHIFT;
    const int hi = min(lo + BW, n);
    const int t = threadIdx.x;

    for (int i = lo + t; i < hi; i += 256) lcur[i - lo] = rowptr[i];
    __syncthreads();

    const int s0 = rowptr[lo], s1 = rowptr[hi];
    for (int i = s0 + t; i < s1; i += 256) {
        uint2 er = staged[i];
        int p = atomicAdd(&lcur[(int)er.x - lo], 1);
        csr[p] = (int)er.y;
    }
}

// ---------------- gatherx: agg{L,N}[v] = sum src[u]*dinv[u] + self ----------

__global__ __launch_bounds__(256) void gatherx_kernel(
    const int* __restrict__ rowptrL, const int* __restrict__ csrL,
    const int* __restrict__ rowptrN, const int* __restrict__ csrN,
    const u32* __restrict__ src,
    const float* __restrict__ dinvL, const float* __restrict__ dinvN,
    u32* __restrict__ aggL, u32* __restrict__ aggN, int n)
{
    const int c  = threadIdx.x & 63;
    const int wv = threadIdx.x >> 6;

    for (int node = blockIdx.x * 4 + wv; node < n; node += gridDim.x * 4) {
        u32 xv = src[(size_t)node * 64 + c];
        float dlv = dinvL[node], dnv = dinvN[node];
        float sL0 = dlv * bf16_lo(xv), sL1 = dlv * bf16_hi(xv);
        float sN0 = dnv * bf16_lo(xv), sN1 = dnv * bf16_hi(xv);

        int jL  = __builtin_amdgcn_readfirstlane(rowptrL[node]);
        int e2L = __builtin_amdgcn_readfirstlane(rowptrL[node + 1]);
        int jN  = __builtin_amdgcn_readfirstlane(rowptrN[node]);
        int e2N = __builtin_amdgcn_readfirstlane(rowptrN[node + 1]);
        const int lenL = e2L - jL;
        const int lenN = e2N - jN;

        int idxL[8], idxN[8];
        if (lenL > 0) {
            #pragma unroll
            for (int k = 0; k < 8; ++k) idxL[k] = csrL[jL + min(k, lenL - 1)];
        }
        if (lenN > 0) {
            #pragma unroll
            for (int k = 0; k < 8; ++k) idxN[k] = csrN[jN + min(k, lenN - 1)];
        }

        const int mx = max(lenL, lenN);
        for (int base = 0; base < mx; base += 8) {
            const bool doL = base < lenL;
            const bool doN = base < lenN;
            u32 aL[8], aN[8];
            float dl[8], dn[8];
            if (doL) {
                #pragma unroll
                for (int k = 0; k < 8; ++k) aL[k] = src[(size_t)idxL[k] * 64 + c];
                #pragma unroll
                for (int k = 0; k < 8; ++k) {
                    float d = dinvL[idxL[k]];
                    dl[k] = (base + k < lenL) ? d : 0.f;
                }
            }
            if (doN) {
                #pragma unroll
                for (int k = 0; k < 8; ++k) aN[k] = src[(size_t)idxN[k] * 64 + c];
                #pragma unroll
                for (int k = 0; k < 8; ++k) {
                    float d = dinvN[idxN[k]];
                    dn[k] = (base + k < lenN) ? d : 0.f;
                }
            }
            if (doL && base + 8 < lenL) {
                #pragma unroll
                for (int k = 0; k < 8; ++k) idxL[k] = csrL[jL + min(base + 8 + k, lenL - 1)];
            }
            if (doN && base + 8 < lenN) {
                #pragma unroll
                for (int k = 0; k < 8; ++k) idxN[k] = csrN[jN + min(base + 8 + k, lenN - 1)];
            }
            if (doL) {
                #pragma unroll
                for (int k = 0; k < 8; ++k) {
                    sL0 = fmaf(dl[k], bf16_lo(aL[k]), sL0);
                    sL1 = fmaf(dl[k], bf16_hi(aL[k]), sL1);
                }
            }
            if (doN) {
                #pragma unroll
                for (int k = 0; k < 8; ++k) {
                    sN0 = fmaf(dn[k], bf16_lo(aN[k]), sN0);
                    sN1 = fmaf(dn[k], bf16_hi(aN[k]), sN1);
                }
            }
        }

        aggL[(size_t)node * 64 + c] = pack_bf16_rne(sL0, sL1);
        aggN[(size_t)node * 64 + c] = pack_bf16_rne(sN0, sN1);
    }
}

// ---------------- combine GEMM ----------------

template<int NCH, bool STATS>
__global__ __launch_bounds__(256) void combine_gemm_kernel(
    const u32* __restrict__ aggL, const u32* __restrict__ aggN, int n,
    const u16* __restrict__ WtL, const u16* __restrict__ WtN,
    const float* __restrict__ dinvL, const float* __restrict__ dinvN,
    const float* __restrict__ cb,
    void* __restrict__ outp,
    float* __restrict__ bn_sum, float* __restrict__ bn_sumsq)
{
    constexpr int CT = NCH / 64;       // ch-tiles per wave: 128->2, 64->1
    __shared__ u16 ls[2][64 * 128];
    __shared__ float bns[128], bnq[128];

    const int t = threadIdx.x;
    const int row0 = blockIdx.x * 64;
    if (STATS && t < 128) { bns[t] = 0.f; bnq[t] = 0.f; }

    const uint4* gL = (const uint4*)aggL;
    const uint4* gN = (const uint4*)aggN;
    #pragma unroll
    for (int i = 0; i < 8; ++i) {
        int flat = i * 256 + t;            // 0..2047
        int table = flat >> 10;
        int q = flat & 1023;
        int r = q >> 4, c16 = q & 15;
        int rr = row0 + r;
        uint4 v = make_uint4(0, 0, 0, 0);
        const uint4* g = table ? gN : gL;
        if (rr < n) v = g[(size_t)rr * 16 + c16];
        int byte = (r * 256 + c16 * 16) ^ ((r & 7) << 4);
        *(uint4*)((char*)(&ls[table][0]) + byte) = v;
    }
    __syncthreads();

    const int l = t & 63, w = t >> 6;
    const int lm = l & 15, lq = l >> 4;
    const int chbase = w * (NCH / 4);

    f32x4 accL[CT][4], accN[CT][4];
    #pragma unroll
    for (int ct = 0; ct < CT; ++ct)
        #pragma unroll
        for (int nt = 0; nt < 4; ++nt) {
            accL[ct][nt] = (f32x4){0.f, 0.f, 0.f, 0.f};
            accN[ct][nt] = (f32x4){0.f, 0.f, 0.f, 0.f};
        }

    #pragma unroll
    for (int ks = 0; ks < 4; ++ks) {
        const int k0 = ks * 32 + lq * 8;
        bf16x8 wfL[CT], wfN[CT];
        #pragma unroll
        for (int ct = 0; ct < CT; ++ct) {
            int ch = chbase + ct * 16 + lm;
            wfL[ct] = *(const bf16x8*)&WtL[(size_t)ch * 128 + k0];
            wfN[ct] = *(const bf16x8*)&WtN[(size_t)ch * 128 + k0];
        }
        #pragma unroll
        for (int nt = 0; nt < 4; ++nt) {
            int m = nt * 16 + lm;
            int byte = (m * 256 + k0 * 2) ^ ((m & 7) << 4);
            bf16x8 xL = *(const bf16x8*)((const char*)(&ls[0][0]) + byte);
            bf16x8 xN = *(const bf16x8*)((const char*)(&ls[1][0]) + byte);
            #pragma unroll
            for (int ct = 0; ct < CT; ++ct) {
                accL[ct][nt] = __builtin_amdgcn_mfma_f32_16x16x32_bf16(
                    wfL[ct], xL, accL[ct][nt], 0, 0, 0);
                accN[ct][nt] = __builtin_amdgcn_mfma_f32_16x16x32_bf16(
                    wfN[ct], xN, accN[ct][nt], 0, 0, 0);
            }
        }
    }

    float sv[CT][4], sq[CT][4];
    #pragma unroll
    for (int ct = 0; ct < CT; ++ct)
        #pragma unroll
        for (int r = 0; r < 4; ++r) { sv[ct][r] = 0.f; sq[ct][r] = 0.f; }

    #pragma unroll
    for (int nt = 0; nt < 4; ++nt) {
        int node = row0 + nt * 16 + lm;
        bool ok = node < n;
        int nodec = ok ? node : 0;
        float dl = ok ? dinvL[nodec] : 0.f;
        float dn = ok ? 0.5f * dinvN[nodec] : 0.f;
        #pragma unroll
        for (int ct = 0; ct < CT; ++ct) {
            int ch0 = chbase + ct * 16 + lq * 4;
            float4 cbv = *(const float4*)&cb[ch0];
            f32x4 aL = accL[ct][nt], aN = accN[ct][nt];
            float v0 = dl * aL[0] + dn * aN[0] + cbv.x;
            float v1 = dl * aL[1] + dn * aN[1] + cbv.y;
            float v2 = dl * aL[2] + dn * aN[2] + cbv.z;
            float v3 = dl * aL[3] + dn * aN[3] + cbv.w;
            if constexpr (STATS) {
                if (ok) {
                    uint2 pk;
                    pk.x = pack_bf16_rne(v0, v1);
                    pk.y = pack_bf16_rne(v2, v3);
                    *(uint2*)&((u32*)outp)[(size_t)node * 64 + (ch0 >> 1)] = pk;
                    sv[ct][0] += v0; sv[ct][1] += v1; sv[ct][2] += v2; sv[ct][3] += v3;
                    sq[ct][0] += v0 * v0; sq[ct][1] += v1 * v1;
                    sq[ct][2] += v2 * v2; sq[ct][3] += v3 * v3;
                }
            } else {
                if (ok)
                    *(float4*)&((float*)outp)[(size_t)node * NCH + ch0] =
                        make_float4(v0, v1, v2, v3);
            }
        }
    }

    if constexpr (STATS) {
        #pragma unroll
        for (int ct = 0; ct < CT; ++ct)
            #pragma unroll
            for (int r = 0; r < 4; ++r) {
                float a = sv[ct][r], b = sq[ct][r];
                #pragma unroll
                for (int m = 1; m <= 8; m <<= 1) {
                    a += __shfl_xor(a, m, 64);
                    b += __shfl_xor(b, m, 64);
                }
                if (lm == 0) {
                    int ch = chbase + ct * 16 + lq * 4 + r;   // unique per writer
                    bns[ch] = a; bnq[ch] = b;
                }
            }
        __syncthreads();
        if (t < 128) {
            atomicAdd(&bn_sum[t], bns[t]);
            atomicAdd(&bn_sumsq[t], bnq[t]);
        }
    }
}

// ---------------- BN finalize + ReLU + bf16 quant: h -> hb ----------------

__global__ __launch_bounds__(256) void bnquant_kernel(
    const u32* __restrict__ h, u32* __restrict__ hb,
    const float* __restrict__ bn_sum, const float* __restrict__ bn_sumsq,
    const float* __restrict__ gamma, const float* __restrict__ beta,
    float inv_n, int total)                     // total = n*64 u32s
{
    __shared__ float sc_s[128], sh_s[128];
    const int t = threadIdx.x;
    if (t < 128) {
        float mean = bn_sum[t] * inv_n;
        float var  = bn_sumsq[t] * inv_n - mean * mean;
        float sc = gamma[t] * rsqrtf(var + 1e-5f);
        sc_s[t] = sc;
        sh_s[t] = beta[t] - mean * sc;
    }
    __syncthreads();

    int i0 = (blockIdx.x * 256 + t) * 4;
    if (i0 + 4 <= total) {
        uint4 v = *(const uint4*)&h[i0];
        u32 r[4];
        u32 vv[4] = {v.x, v.y, v.z, v.w};
        #pragma unroll
        for (int j = 0; j < 4; ++j) {
            int cp = (i0 + j) & 63;
            float a = fmaxf(bf16_lo(vv[j]) * sc_s[2 * cp]     + sh_s[2 * cp],     0.f);
            float b = fmaxf(bf16_hi(vv[j]) * sc_s[2 * cp + 1] + sh_s[2 * cp + 1], 0.f);
            r[j] = pack_bf16_rne(a, b);
        }
        *(uint4*)&hb[i0] = make_uint4(r[0], r[1], r[2], r[3]);
    } else {
        for (int i = i0; i < total; ++i) {
            int cp = i & 63;
            u32 u = h[i];
            float a = fmaxf(bf16_lo(u) * sc_s[2 * cp]     + sh_s[2 * cp],     0.f);
            float b = fmaxf(bf16_hi(u) * sc_s[2 * cp + 1] + sh_s[2 * cp + 1], 0.f);
            hb[i] = pack_bf16_rne(a, b);
        }
    }
}

// ---------------- launch ----------------

extern "C" void kernel_launch(void* const* d_in, const int* in_sizes, int n_in,
                              void* d_out, int out_size, void* d_ws, size_t ws_size,
                              hipStream_t stream)
{
    const float* x     = (const float*)d_in[0];
    const int*   adjL  = (const int*)d_in[1];   // adj_low
    const int*   adjN  = (const int*)d_in[3];   // adj_nd_low
    const float* W1L   = (const float*)d_in[5];
    const float* b1L   = (const float*)d_in[6];
    const float* W1N   = (const float*)d_in[7];
    const float* b1N   = (const float*)d_in[8];
    const float* gamma = (const float*)d_in[9];
    const float* beta  = (const float*)d_in[10];
    const float* W2L   = (const float*)d_in[11];
    const float* b2L   = (const float*)d_in[12];
    const float* W2N   = (const float*)d_in[13];
    const float* b2N   = (const float*)d_in[14];

    const int n  = in_sizes[0] / 128;
    const int eL = in_sizes[1] / 2;
    const int eN = in_sizes[3] / 2;
    const int* rowL = adjL;  const int* colL = adjL + eL;
    const int* rowN = adjN;  const int* colN = adjN + eN;
    const int nb = idiv_up(n, BW);      // == scan tile count, <= 64

    char* p = (char*)d_ws;
    const size_t tb = (size_t)n * 128 * sizeof(u16);    // bf16 [n][128] table
    u32* xb   = (u32*)p; p += tb;       // x bf16; later aliased by hb
    u32* aggL = (u32*)p; p += tb;       // layer agg tables (reused both layers)
    u32* aggN = (u32*)p; p += tb;
    u32* h    = (u32*)p; p += tb;       // h bf16; earlier aliased by staged
    float* dinvL = (float*)p; p += (size_t)n * sizeof(float);
    float* dinvN = (float*)p; p += (size_t)n * sizeof(float);
    float* bn_sum   = (float*)p; p += 128 * sizeof(float);
    float* bn_sumsq = (float*)p; p += 128 * sizeof(float);
    float* cb1 = (float*)p; p += 128 * sizeof(float);
    float* cb2 = (float*)p; p += 64 * sizeof(float);
    int* degL    = (int*)p; p += (size_t)n * sizeof(int);
    int* degN    = (int*)p; p += (size_t)n * sizeof(int);
    int* rowptrL = (int*)p; p += (size_t)(n + 1) * sizeof(int);
    int* rowptrN = (int*)p; p += (size_t)(n + 1) * sizeof(int);
    int* gcurL   = (int*)p; p += 64 * sizeof(int);
    int* gcurN   = (int*)p; p += 64 * sizeof(int);
    int* psum    = (int*)p; p += 128 * sizeof(int);
    int* csrL    = (int*)p; p += (size_t)eL * sizeof(int);
    int* csrN    = (int*)p; p += (size_t)eN * sizeof(int);
    u16* WtL1 = (u16*)p; p += 128 * 128 * sizeof(u16);
    u16* WtN1 = (u16*)p; p += 128 * 128 * sizeof(u16);
    u16* WtL2 = (u16*)p; p += 64 * 128 * sizeof(u16);
    u16* WtN2 = (u16*)p; p += 64 * 128 * sizeof(u16);

    // staged (eL+eN uint2 = 25.6 MB) aliases h: staged dead after binB;
    // h written first by combine_gemm<128> (after binB). Stream-ordered.
    uint2* stagedL = (uint2*)h;
    uint2* stagedN = stagedL + eL;
    // hb aliases xb: xb dead after first gatherx; hb written by bnquant later.
    u32* hb = xb;

    hipMemsetAsync(degL, 0, (size_t)n * 2 * sizeof(int), stream);
    hipMemsetAsync(bn_sum, 0, 2 * 128 * sizeof(float), stream);

    const int emax = eL > eN ? eL : eN;

    // 1. count_deg ∥ wprep ∥ combined-bias
    const int nCount = idiv_up(emax >> 2, 256);
    prep_kernel<<<nCount + 256 + 1, 256, 0, stream>>>(
        colL, colN, eL, eN, degL, degN,
        W1L, W1N, W2L, W2N, WtL1, WtN1, WtL2, WtN2,
        b1L, b1N, b2L, b2N, cb1, cb2, nCount);

    // 2. parallel scan (A: tile sums, B: offsets+gcur, C: rowptr+dinv)
    const int nt = idiv_up(n, STILE);
    scanA_kernel<<<dim3(nt, 2), 256, 0, stream>>>(degL, degN, n, psum);
    scanB_kernel<<<1, 64, 0, stream>>>(psum, nt, rowptrL, rowptrN,
                                       gcurL, gcurN, n);
    scanC_kernel<<<dim3(nt, 2), 256, 0, stream>>>(
        degL, degN, n, psum, rowptrL, rowptrN, dinvL, dinvN);

    // 3. binA ∥ x->bf16
    const int nA = idiv_up(emax, ACHUNK);
    const int nx4 = n * 32;
    binA_xq_kernel<<<2 * nA + idiv_up(nx4, 256), 256, 0, stream>>>(
        rowL, colL, eL, rowN, colN, eN, gcurL, gcurN, stagedL, stagedN, nb, nA,
        x, xb, nx4);

    // 4. binB
    binB_kernel<<<dim3(nb, 2), 256, 0, stream>>>(
        rowptrL, rowptrN, stagedL, stagedN, csrL, csrN, n);

    // 5. layer-1 gather in x-space (single 25.6 MB table)
    gatherx_kernel<<<4096, 256, 0, stream>>>(
        rowptrL, csrL, rowptrN, csrN, xb, dinvL, dinvN, aggL, aggN, n);

    // 6. layer-1 combine GEMM (+BN stats) -> h bf16
    combine_gemm_kernel<128, true><<<idiv_up(n, 64), 256, 0, stream>>>(
        aggL, aggN, n, WtL1, WtN1, dinvL, dinvN, cb1, h, bn_sum, bn_sumsq);

    // 7. BN finalize + ReLU + quant -> hb
    bnquant_kernel<<<idiv_up(n * 64, 1024), 256, 0, stream>>>(
        h, hb, bn_sum, bn_sumsq, gamma, beta, 1.0f / (float)n, n * 64);

    // 8. layer-2 gather in h-space (single 25.6 MB table)
    gatherx_kernel<<<4096, 256, 0, stream>>>(
        rowptrL, csrL, rowptrN, csrN, hb, dinvL, dinvN, aggL, aggN, n);

    // 9. layer-2 combine GEMM -> d_out fp32
    combine_gemm_kernel<64, false><<<idiv_up(n, 64), 256, 0, stream>>>(
        aggL, aggN, n, WtL2, WtN2, dinvL, dinvN, cb2, d_out, nullptr, nullptr);
}

// Round 14
// 561.642 us; speedup vs baseline: 1.4249x; 1.1059x over previous
//
#include <hip/hip_runtime.h>

typedef unsigned int u32;
typedef unsigned short u16;
using bf16x8 = __attribute__((ext_vector_type(8))) short;
using f32x4  = __attribute__((ext_vector_type(4))) float;

static inline int idiv_up(int a, int b) { return (a + b - 1) / b; }

#define BSHIFT 11          // bucket width 2048 nodes
#define BW     2048
#define STILE  2048        // scan tile == BW so gcur[b] = tile offset
#define ACHUNK 8192        // edges per binA block

// ---------------- bf16 pack/unpack ----------------

__device__ __forceinline__ u32 pack_bf16_rne(float lo, float hi) {
    u32 ul = __float_as_uint(lo);
    u32 uh = __float_as_uint(hi);
    ul = (ul + 0x7fffu + ((ul >> 16) & 1u)) >> 16;
    uh = (uh + 0x7fffu + ((uh >> 16) & 1u));
    return (ul & 0xffffu) | (uh & 0xffff0000u);
}
__device__ __forceinline__ u16 bf16_rne1(float v) {
    u32 u = __float_as_uint(v);
    return (u16)((u + 0x7fffu + ((u >> 16) & 1u)) >> 16);
}
__device__ __forceinline__ float bf16_lo(u32 u) { return __uint_as_float(u << 16); }
__device__ __forceinline__ float bf16_hi(u32 u) { return __uint_as_float(u & 0xffff0000u); }

// ---------------- fused: count_deg (int4) ∥ wprep ∥ combined-bias ----------------

__global__ __launch_bounds__(256) void prep_kernel(
    const int* __restrict__ colL, const int* __restrict__ colN,
    int eL, int eN,
    int* __restrict__ degL, int* __restrict__ degN,
    const float* __restrict__ W1L, const float* __restrict__ W1N,
    const float* __restrict__ W2L, const float* __restrict__ W2N,
    u16* __restrict__ T1L, u16* __restrict__ T1N,
    u16* __restrict__ T2L, u16* __restrict__ T2N,
    const float* __restrict__ b1L, const float* __restrict__ b1N,
    const float* __restrict__ b2L, const float* __restrict__ b2N,
    float* __restrict__ cb1, float* __restrict__ cb2,
    int nCount)
{
    const int t = threadIdx.x;
    if ((int)blockIdx.x < nCount) {
        int i4 = blockIdx.x * 256 + t;
        if (i4 < (eL >> 2)) {
            int4 c = ((const int4*)colL)[i4];
            atomicAdd(&degL[c.x], 1); atomicAdd(&degL[c.y], 1);
            atomicAdd(&degL[c.z], 1); atomicAdd(&degL[c.w], 1);
        }
        if (i4 < (eN >> 2)) {
            int4 c = ((const int4*)colN)[i4];
            atomicAdd(&degN[c.x], 1); atomicAdd(&degN[c.y], 1);
            atomicAdd(&degN[c.z], 1); atomicAdd(&degN[c.w], 1);
        }
        if (blockIdx.x == 0) {
            if (t < (eL & 3)) atomicAdd(&degL[colL[(eL & ~3) + t]], 1);
            if (t < (eN & 3)) atomicAdd(&degN[colN[(eN & ~3) + t]], 1);
        }
    } else if ((int)blockIdx.x < nCount + 256) {
        int b = blockIdx.x - nCount;          // 0..255
        int which = b >> 6, bx = b & 63;
        const float* src = which == 0 ? W1L : which == 1 ? W1N : which == 2 ? W2L : W2N;
        u16* dst         = which == 0 ? T1L : which == 1 ? T1N : which == 2 ? T2L : T2N;
        const int nc = which < 2 ? 128 : 64;
        int i = bx * 256 + t;
        if (i < 128 * nc) {
            int k = i / nc, nn = i % nc;
            dst[nn * 128 + k] = bf16_rne1(src[i]);
        }
    } else {
        if (t < 128) cb1[t] = b1L[t] + 0.5f * b1N[t];
        if (t < 64)  cb2[t] = b2L[t] + 0.5f * b2N[t];
    }
}

// ---------------- parallel scan, phase A: per-tile sums ----------------

__global__ __launch_bounds__(256) void scanA_kernel(
    const int* __restrict__ degL, const int* __restrict__ degN, int n,
    int* __restrict__ psum)
{
    const int adj = blockIdx.y;
    const int* deg = adj ? degN : degL;
    const int t = threadIdx.x;
    const int base = blockIdx.x * STILE + t * 8;
    int s = 0;
    #pragma unroll
    for (int j = 0; j < 8; ++j) {
        int idx = base + j;
        if (idx < n) s += deg[idx];
    }
    __shared__ int ls[256];
    ls[t] = s;
    __syncthreads();
    for (int off = 128; off > 0; off >>= 1) {
        if (t < off) ls[t] += ls[t + off];
        __syncthreads();
    }
    if (t == 0) psum[adj * 64 + blockIdx.x] = ls[0];
}

// ---------------- phase B: wave-scan partials -> tile offsets, gcur, rowptr[n]

__global__ __launch_bounds__(64) void scanB_kernel(
    int* __restrict__ psum, int nt,
    int* __restrict__ rowptrL, int* __restrict__ rowptrN,
    int* __restrict__ gcurL, int* __restrict__ gcurN, int n)
{
    const int l = threadIdx.x;   // 64 lanes; nt <= 64
    #pragma unroll
    for (int adj = 0; adj < 2; ++adj) {
        int v = (l < nt) ? psum[adj * 64 + l] : 0;
        int orig = v;
        for (int off = 1; off < 64; off <<= 1) {
            int u = __shfl_up(v, off, 64);
            if (l >= off) v += u;
        }
        int excl = v - orig;
        if (l < nt) {
            psum[adj * 64 + l] = excl;
            int* gcur = adj ? gcurN : gcurL;
            gcur[l] = excl;
        }
        if (l == 63) {
            int* rowptr = adj ? rowptrN : rowptrL;
            rowptr[n] = v;
        }
    }
}

// ---------------- fused: binA (packed staged) ∥ x->bf16 ∥ scanC ----------------
// staged entry: (row << 11) | (col & 2047)  [n < 2^17, buckets 2048-aligned]

__global__ __launch_bounds__(256) void binA_xq_scanC_kernel(
    const int* __restrict__ rowL, const int* __restrict__ colL, int eL,
    const int* __restrict__ rowN, const int* __restrict__ colN, int eN,
    int* __restrict__ gcurL, int* __restrict__ gcurN,
    u32* __restrict__ stagedL, u32* __restrict__ stagedN, int nb, int nA,
    const float* __restrict__ x, u32* __restrict__ xb, int nx4, int nxq,
    const int* __restrict__ degL, const int* __restrict__ degN, int n,
    const int* __restrict__ psum,
    int* __restrict__ rowptrL, int* __restrict__ rowptrN,
    float* __restrict__ dinvL, float* __restrict__ dinvN, int ntile)
{
    __shared__ int sh_hist[64];
    __shared__ int sh_base[64];
    __shared__ int sh_scan[256];
    const int t = threadIdx.x;
    const int bid = blockIdx.x;

    if (bid < 2 * nA) {
        const int adj = bid >= nA;
        const int chunkb = adj ? bid - nA : bid;
        const int* rowA = adj ? rowN : rowL;
        const int* colA = adj ? colN : colL;
        const int e     = adj ? eN   : eL;
        int* gcur       = adj ? gcurN : gcurL;
        u32* staged     = adj ? stagedN : stagedL;

        if (t < 64) sh_hist[t] = 0;
        __syncthreads();

        const int i0 = chunkb * ACHUNK;
        const int i1 = min(i0 + ACHUNK, e);

        for (int i = i0 + t; i < i1; i += 256)
            atomicAdd(&sh_hist[colA[i] >> BSHIFT], 1);
        __syncthreads();

        if (t < 64) {
            int cnt = sh_hist[t];
            if (t < nb && cnt > 0) sh_base[t] = atomicAdd(&gcur[t], cnt);
        }
        __syncthreads();
        if (t < 64) sh_hist[t] = 0;
        __syncthreads();

        for (int i = i0 + t; i < i1; i += 256) {
            int c = colA[i], r = rowA[i];
            int b = c >> BSHIFT;
            int pos = sh_base[b] + atomicAdd(&sh_hist[b], 1);
            staged[pos] = ((u32)r << BSHIFT) | ((u32)c & (BW - 1));
        }
    } else if (bid < 2 * nA + nxq) {
        int i4 = (bid - 2 * nA) * 256 + t;
        if (i4 < nx4) {
            float4 v = ((const float4*)x)[i4];
            ((uint2*)xb)[i4] = make_uint2(pack_bf16_rne(v.x, v.y),
                                          pack_bf16_rne(v.z, v.w));
        }
    } else {
        int b = bid - 2 * nA - nxq;
        const int adj = b >= ntile;
        const int tile = adj ? b - ntile : b;
        const int* deg = adj ? degN : degL;
        int* rowptr    = adj ? rowptrN : rowptrL;
        float* dinv    = adj ? dinvN : dinvL;
        const int base = tile * STILE + t * 8;

        int d[8]; int s = 0;
        #pragma unroll
        for (int j = 0; j < 8; ++j) {
            int idx = base + j;
            d[j] = (idx < n) ? deg[idx] : 0;
            s += d[j];
        }
        sh_scan[t] = s;
        __syncthreads();
        for (int off = 1; off < 256; off <<= 1) {
            int a = (t >= off) ? sh_scan[t - off] : 0;
            __syncthreads();
            sh_scan[t] += a;
            __syncthreads();
        }
        int running = psum[adj * 64 + tile] + sh_scan[t] - s;
        #pragma unroll
        for (int j = 0; j < 8; ++j) {
            int idx = base + j;
            if (idx < n) {
                rowptr[idx] = running;
                running += d[j];
                dinv[idx] = rsqrtf((float)d[j] + 1.0f);   // +1 self loop
            }
        }
    }
}

// ---------------- radix pass B (packed staged) ----------------

__global__ __launch_bounds__(256) void binB_kernel(
    const int* __restrict__ rowptrL, const int* __restrict__ rowptrN,
    const u32* __restrict__ stagedL, const u32* __restrict__ stagedN,
    int* __restrict__ csrL, int* __restrict__ csrN, int n)
{
    const int adj = blockIdx.y;
    const int* rowptr = adj ? rowptrN : rowptrL;
    const u32* staged = adj ? stagedN : stagedL;
    int* csr          = adj ? csrN    : csrL;

    __shared__ int lcur[BW];
    const int lo = blockIdx.x << BSHIFT;
    const int hi = min(lo + BW, n);
    const int t = threadIdx.x;

    for (int i = lo + t; i < hi; i += 256) lcur[i - lo] = rowptr[i];
    __syncthreads();

    const int s0 = rowptr[lo], s1 = rowptr[hi];
    for (int i = s0 + t; i < s1; i += 256) {
        u32 v = staged[i];
        int p = atomicAdd(&lcur[v & (BW - 1)], 1);
        csr[p] = (int)(v >> BSHIFT);
    }
}

// ---------------- fused gather + combine-GEMM ----------------
// 512 threads / 8 waves; block owns 64 nodes. Wave w gathers 8 nodes' agg
// rows (dual-stream, 8-deep pipelined, per-source dinv fused) into registers,
// stages bf16 to XOR-swizzled LDS, then the verified 16x16x32 MFMA path:
// Wt = A-operand (rows=out-channels), agg = B-operand (cols=nodes); lane
// holds 4 consecutive out-channels of one node. L/N combined in-register.
// STATS (layer1): bf16 h out + BN sum/sumsq. else fp32 out.

template<int NCH, bool STATS>
__global__ __launch_bounds__(512) void fused_gg_kernel(
    const int* __restrict__ rowptrL, const int* __restrict__ csrL,
    const int* __restrict__ rowptrN, const int* __restrict__ csrN,
    const u32* __restrict__ src,
    const u16* __restrict__ WtL, const u16* __restrict__ WtN,
    const float* __restrict__ dinvL, const float* __restrict__ dinvN,
    const float* __restrict__ cb, void* __restrict__ outp, int n,
    float* __restrict__ bn_sum, float* __restrict__ bn_sumsq)
{
    constexpr int NTN = (NCH == 128) ? 4 : 2;   // node-tiles per wave
    __shared__ u16 ls[2][64 * 128];
    __shared__ float bns[128], bnq[128];

    const int t = threadIdx.x;
    const int l = t & 63, w = t >> 6;
    const int row0 = blockIdx.x * 64;
    if (STATS && t < 128) { bns[t] = 0.f; bnq[t] = 0.f; }

    // ---- gather phase: wave w -> rows w*8 .. w*8+7
    for (int i = 0; i < 8; ++i) {
        const int r = w * 8 + i;
        const int node = row0 + r;
        u32 packL = 0, packN = 0;
        if (node < n) {
            u32 xv = src[(size_t)node * 64 + l];
            float dlv = dinvL[node], dnv = dinvN[node];
            float sL0 = dlv * bf16_lo(xv), sL1 = dlv * bf16_hi(xv);
            float sN0 = dnv * bf16_lo(xv), sN1 = dnv * bf16_hi(xv);

            int jL  = __builtin_amdgcn_readfirstlane(rowptrL[node]);
            int e2L = __builtin_amdgcn_readfirstlane(rowptrL[node + 1]);
            int jN  = __builtin_amdgcn_readfirstlane(rowptrN[node]);
            int e2N = __builtin_amdgcn_readfirstlane(rowptrN[node + 1]);
            const int lenL = e2L - jL;
            const int lenN = e2N - jN;

            int idxL[8], idxN[8];
            if (lenL > 0) {
                #pragma unroll
                for (int k = 0; k < 8; ++k) idxL[k] = csrL[jL + min(k, lenL - 1)];
            }
            if (lenN > 0) {
                #pragma unroll
                for (int k = 0; k < 8; ++k) idxN[k] = csrN[jN + min(k, lenN - 1)];
            }

            const int mx = max(lenL, lenN);
            for (int base = 0; base < mx; base += 8) {
                const bool doL = base < lenL;
                const bool doN = base < lenN;
                u32 aL[8], aN[8];
                float dl[8], dn[8];
                if (doL) {
                    #pragma unroll
                    for (int k = 0; k < 8; ++k) aL[k] = src[(size_t)idxL[k] * 64 + l];
                    #pragma unroll
                    for (int k = 0; k < 8; ++k) {
                        float d = dinvL[idxL[k]];
                        dl[k] = (base + k < lenL) ? d : 0.f;
                    }
                }
                if (doN) {
                    #pragma unroll
                    for (int k = 0; k < 8; ++k) aN[k] = src[(size_t)idxN[k] * 64 + l];
                    #pragma unroll
                    for (int k = 0; k < 8; ++k) {
                        float d = dinvN[idxN[k]];
                        dn[k] = (base + k < lenN) ? d : 0.f;
                    }
                }
                if (doL && base + 8 < lenL) {
                    #pragma unroll
                    for (int k = 0; k < 8; ++k) idxL[k] = csrL[jL + min(base + 8 + k, lenL - 1)];
                }
                if (doN && base + 8 < lenN) {
                    #pragma unroll
                    for (int k = 0; k < 8; ++k) idxN[k] = csrN[jN + min(base + 8 + k, lenN - 1)];
                }
                if (doL) {
                    #pragma unroll
                    for (int k = 0; k < 8; ++k) {
                        sL0 = fmaf(dl[k], bf16_lo(aL[k]), sL0);
                        sL1 = fmaf(dl[k], bf16_hi(aL[k]), sL1);
                    }
                }
                if (doN) {
                    #pragma unroll
                    for (int k = 0; k < 8; ++k) {
                        sN0 = fmaf(dn[k], bf16_lo(aN[k]), sN0);
                        sN1 = fmaf(dn[k], bf16_hi(aN[k]), sN1);
                    }
                }
            }
            packL = pack_bf16_rne(sL0, sL1);
            packN = pack_bf16_rne(sN0, sN1);
        }
        const int byte = (r * 256 + l * 4) ^ ((r & 7) << 4);
        *(u32*)((char*)&ls[0][0] + byte) = packL;
        *(u32*)((char*)&ls[1][0] + byte) = packN;
    }
    __syncthreads();

    // ---- MFMA phase
    const int lm = l & 15, lq = l >> 4;
    const int chbase = (NCH == 128) ? w * 16 : (w & 3) * 16;
    const int nt0    = (NCH == 128) ? 0 : (w >> 2) * 2;

    f32x4 accL[NTN], accN[NTN];
    #pragma unroll
    for (int q = 0; q < NTN; ++q) {
        accL[q] = (f32x4){0.f, 0.f, 0.f, 0.f};
        accN[q] = (f32x4){0.f, 0.f, 0.f, 0.f};
    }

    #pragma unroll
    for (int ks = 0; ks < 4; ++ks) {
        const int k0 = ks * 32 + lq * 8;
        bf16x8 wfL = *(const bf16x8*)&WtL[(size_t)(chbase + lm) * 128 + k0];
        bf16x8 wfN = *(const bf16x8*)&WtN[(size_t)(chbase + lm) * 128 + k0];
        #pragma unroll
        for (int q = 0; q < NTN; ++q) {
            const int m = (nt0 + q) * 16 + lm;
            const int byte = (m * 256 + k0 * 2) ^ ((m & 7) << 4);
            bf16x8 xL = *(const bf16x8*)((const char*)&ls[0][0] + byte);
            bf16x8 xN = *(const bf16x8*)((const char*)&ls[1][0] + byte);
            accL[q] = __builtin_amdgcn_mfma_f32_16x16x32_bf16(wfL, xL, accL[q], 0, 0, 0);
            accN[q] = __builtin_amdgcn_mfma_f32_16x16x32_bf16(wfN, xN, accN[q], 0, 0, 0);
        }
    }

    // ---- epilogue
    float sv[4] = {0.f, 0.f, 0.f, 0.f}, sq[4] = {0.f, 0.f, 0.f, 0.f};
    const int ch0 = chbase + lq * 4;
    const float4 cbv = *(const float4*)&cb[ch0];

    #pragma unroll
    for (int q = 0; q < NTN; ++q) {
        const int node = row0 + (nt0 + q) * 16 + lm;
        const bool ok = node < n;
        const int nodec = ok ? node : 0;
        float dl = ok ? dinvL[nodec] : 0.f;
        float dn = ok ? 0.5f * dinvN[nodec] : 0.f;
        f32x4 aL = accL[q], aN = accN[q];
        float v0 = dl * aL[0] + dn * aN[0] + cbv.x;
        float v1 = dl * aL[1] + dn * aN[1] + cbv.y;
        float v2 = dl * aL[2] + dn * aN[2] + cbv.z;
        float v3 = dl * aL[3] + dn * aN[3] + cbv.w;
        if constexpr (STATS) {
            if (ok) {
                uint2 pk;
                pk.x = pack_bf16_rne(v0, v1);
                pk.y = pack_bf16_rne(v2, v3);
                *(uint2*)&((u32*)outp)[(size_t)node * 64 + (ch0 >> 1)] = pk;
                sv[0] += v0; sv[1] += v1; sv[2] += v2; sv[3] += v3;
                sq[0] += v0 * v0; sq[1] += v1 * v1; sq[2] += v2 * v2; sq[3] += v3 * v3;
            }
        } else {
            if (ok)
                *(float4*)&((float*)outp)[(size_t)node * NCH + ch0] =
                    make_float4(v0, v1, v2, v3);
        }
    }

    if constexpr (STATS) {
        #pragma unroll
        for (int r = 0; r < 4; ++r) {
            float a = sv[r], b = sq[r];
            #pragma unroll
            for (int m = 1; m <= 8; m <<= 1) {
                a += __shfl_xor(a, m, 64);
                b += __shfl_xor(b, m, 64);
            }
            if (lm == 0) {
                bns[ch0 + r] = a;
                bnq[ch0 + r] = b;
            }
        }
        __syncthreads();
        if (t < 128) {
            atomicAdd(&bn_sum[t], bns[t]);
            atomicAdd(&bn_sumsq[t], bnq[t]);
        }
    }
}

// ---------------- BN finalize + ReLU + bf16 quant: h -> hb ----------------

__global__ __launch_bounds__(256) void bnquant_kernel(
    const u32* __restrict__ h, u32* __restrict__ hb,
    const float* __restrict__ bn_sum, const float* __restrict__ bn_sumsq,
    const float* __restrict__ gamma, const float* __restrict__ beta,
    float inv_n, int total)                     // total = n*64 u32s
{
    __shared__ float sc_s[128], sh_s[128];
    const int t = threadIdx.x;
    if (t < 128) {
        float mean = bn_sum[t] * inv_n;
        float var  = bn_sumsq[t] * inv_n - mean * mean;
        float sc = gamma[t] * rsqrtf(var + 1e-5f);
        sc_s[t] = sc;
        sh_s[t] = beta[t] - mean * sc;
    }
    __syncthreads();

    int i0 = (blockIdx.x * 256 + t) * 4;
    if (i0 + 4 <= total) {
        uint4 v = *(const uint4*)&h[i0];
        u32 r[4];
        u32 vv[4] = {v.x, v.y, v.z, v.w};
        #pragma unroll
        for (int j = 0; j < 4; ++j) {
            int cp = (i0 + j) & 63;
            float a = fmaxf(bf16_lo(vv[j]) * sc_s[2 * cp]     + sh_s[2 * cp],     0.f);
            float b = fmaxf(bf16_hi(vv[j]) * sc_s[2 * cp + 1] + sh_s[2 * cp + 1], 0.f);
            r[j] = pack_bf16_rne(a, b);
        }
        *(uint4*)&hb[i0] = make_uint4(r[0], r[1], r[2], r[3]);
    } else {
        for (int i = i0; i < total; ++i) {
            int cp = i & 63;
            u32 u = h[i];
            float a = fmaxf(bf16_lo(u) * sc_s[2 * cp]     + sh_s[2 * cp],     0.f);
            float b = fmaxf(bf16_hi(u) * sc_s[2 * cp + 1] + sh_s[2 * cp + 1], 0.f);
            hb[i] = pack_bf16_rne(a, b);
        }
    }
}

// ---------------- launch ----------------

extern "C" void kernel_launch(void* const* d_in, const int* in_sizes, int n_in,
                              void* d_out, int out_size, void* d_ws, size_t ws_size,
                              hipStream_t stream)
{
    const float* x     = (const float*)d_in[0];
    const int*   adjL  = (const int*)d_in[1];   // adj_low
    const int*   adjN  = (const int*)d_in[3];   // adj_nd_low
    const float* W1L   = (const float*)d_in[5];
    const float* b1L   = (const float*)d_in[6];
    const float* W1N   = (const float*)d_in[7];
    const float* b1N   = (const float*)d_in[8];
    const float* gamma = (const float*)d_in[9];
    const float* beta  = (const float*)d_in[10];
    const float* W2L   = (const float*)d_in[11];
    const float* b2L   = (const float*)d_in[12];
    const float* W2N   = (const float*)d_in[13];
    const float* b2N   = (const float*)d_in[14];

    const int n  = in_sizes[0] / 128;
    const int eL = in_sizes[1] / 2;
    const int eN = in_sizes[3] / 2;
    const int* rowL = adjL;  const int* colL = adjL + eL;
    const int* rowN = adjN;  const int* colN = adjN + eN;
    const int nb = idiv_up(n, BW);      // buckets == scan tiles, <= 64

    char* p = (char*)d_ws;
    const size_t tb = (size_t)n * 128 * sizeof(u16);    // bf16 [n][128] table
    u32* xb = (u32*)p; p += tb;         // x bf16; later aliased by hb
    u32* h  = (u32*)p; p += tb;         // h bf16; earlier aliased by staged
    float* dinvL = (float*)p; p += (size_t)n * sizeof(float);
    float* dinvN = (float*)p; p += (size_t)n * sizeof(float);
    float* bn_sum   = (float*)p; p += 128 * sizeof(float);
    float* bn_sumsq = (float*)p; p += 128 * sizeof(float);
    float* cb1 = (float*)p; p += 128 * sizeof(float);
    float* cb2 = (float*)p; p += 64 * sizeof(float);
    int* degL    = (int*)p; p += (size_t)n * sizeof(int);
    int* degN    = (int*)p; p += (size_t)n * sizeof(int);
    int* rowptrL = (int*)p; p += (size_t)(n + 1) * sizeof(int);
    int* rowptrN = (int*)p; p += (size_t)(n + 1) * sizeof(int);
    int* gcurL   = (int*)p; p += 64 * sizeof(int);
    int* gcurN   = (int*)p; p += 64 * sizeof(int);
    int* psum    = (int*)p; p += 128 * sizeof(int);
    int* csrL    = (int*)p; p += (size_t)eL * sizeof(int);
    int* csrN    = (int*)p; p += (size_t)eN * sizeof(int);
    u16* WtL1 = (u16*)p; p += 128 * 128 * sizeof(u16);
    u16* WtN1 = (u16*)p; p += 128 * 128 * sizeof(u16);
    u16* WtL2 = (u16*)p; p += 64 * 128 * sizeof(u16);
    u16* WtN2 = (u16*)p; p += 64 * 128 * sizeof(u16);

    // staged (eL+eN u32 = 12.8 MB) aliases h (25.6 MB): staged dead after
    // binB; h written first by fused_gg<128> (after binB). Stream-ordered.
    u32* stagedL = (u32*)h;
    u32* stagedN = stagedL + eL;
    // hb aliases xb: xb dead after fused_gg<128>'s gather; hb written by
    // bnquant afterwards.
    u32* hb = xb;

    hipMemsetAsync(degL, 0, (size_t)n * 2 * sizeof(int), stream);
    hipMemsetAsync(bn_sum, 0, 2 * 128 * sizeof(float), stream);

    const int emax = eL > eN ? eL : eN;

    // 1. count_deg ∥ wprep ∥ combined-bias
    const int nCount = idiv_up(emax >> 2, 256);
    prep_kernel<<<nCount + 256 + 1, 256, 0, stream>>>(
        colL, colN, eL, eN, degL, degN,
        W1L, W1N, W2L, W2N, WtL1, WtN1, WtL2, WtN2,
        b1L, b1N, b2L, b2N, cb1, cb2, nCount);

    // 2. scan phases A, B
    const int nt = idiv_up(n, STILE);
    scanA_kernel<<<dim3(nt, 2), 256, 0, stream>>>(degL, degN, n, psum);
    scanB_kernel<<<1, 64, 0, stream>>>(psum, nt, rowptrL, rowptrN,
                                       gcurL, gcurN, n);

    // 3. binA ∥ x->bf16 ∥ scanC
    const int nA = idiv_up(emax, ACHUNK);
    const int nx4 = n * 32;
    const int nxq = idiv_up(nx4, 256);
    binA_xq_scanC_kernel<<<2 * nA + nxq + 2 * nt, 256, 0, stream>>>(
        rowL, colL, eL, rowN, colN, eN, gcurL, gcurN, stagedL, stagedN, nb, nA,
        x, xb, nx4, nxq,
        degL, degN, n, psum, rowptrL, rowptrN, dinvL, dinvN, nt);

    // 4. binB
    binB_kernel<<<dim3(nb, 2), 256, 0, stream>>>(
        rowptrL, rowptrN, stagedL, stagedN, csrL, csrN, n);

    // 5. layer-1 fused gather+GEMM (+BN stats) -> h bf16
    fused_gg_kernel<128, true><<<idiv_up(n, 64), 512, 0, stream>>>(
        rowptrL, csrL, rowptrN, csrN, xb, WtL1, WtN1, dinvL, dinvN,
        cb1, h, n, bn_sum, bn_sumsq);

    // 6. BN finalize + ReLU + quant -> hb
    bnquant_kernel<<<idiv_up(n * 64, 1024), 256, 0, stream>>>(
        h, hb, bn_sum, bn_sumsq, gamma, beta, 1.0f / (float)n, n * 64);

    // 7. layer-2 fused gather+GEMM -> d_out fp32
    fused_gg_kernel<64, false><<<idiv_up(n, 64), 512, 0, stream>>>(
        rowptrL, csrL, rowptrN, csrN, hb, WtL2, WtN2, dinvL, dinvN,
        cb2, d_out, n, nullptr, nullptr);
}

// Round 15
// 473.321 us; speedup vs baseline: 1.6908x; 1.1866x over previous
//
#include <hip/hip_runtime.h>

typedef unsigned int u32;
typedef unsigned short u16;
using bf16x8 = __attribute__((ext_vector_type(8))) short;
using f32x4  = __attribute__((ext_vector_type(4))) float;

static inline int idiv_up(int a, int b) { return (a + b - 1) / b; }

#define BSHIFT 11          // bucket width 2048 nodes
#define BW     2048
#define ACHUNK 8192        // edges per binA block
#define HCHUNK 4096        // int4s per hist block

// ---------------- bf16 pack/unpack ----------------

__device__ __forceinline__ u32 pack_bf16_rne(float lo, float hi) {
    u32 ul = __float_as_uint(lo);
    u32 uh = __float_as_uint(hi);
    ul = (ul + 0x7fffu + ((ul >> 16) & 1u)) >> 16;
    uh = (uh + 0x7fffu + ((uh >> 16) & 1u));
    return (ul & 0xffffu) | (uh & 0xffff0000u);
}
__device__ __forceinline__ u16 bf16_rne1(float v) {
    u32 u = __float_as_uint(v);
    return (u16)((u + 0x7fffu + ((u >> 16) & 1u)) >> 16);
}
__device__ __forceinline__ float bf16_lo(u32 u) { return __uint_as_float(u << 16); }
__device__ __forceinline__ float bf16_hi(u32 u) { return __uint_as_float(u & 0xffff0000u); }

// -------- prep2: bucket-hist ∥ wprep ∥ combined-bias ∥ x->bf16 --------

__global__ __launch_bounds__(256) void prep2_kernel(
    const int* __restrict__ colL, const int* __restrict__ colN,
    int eL, int eN, int* __restrict__ bcnt,
    const float* __restrict__ W1L, const float* __restrict__ W1N,
    const float* __restrict__ W2L, const float* __restrict__ W2N,
    u16* __restrict__ T1L, u16* __restrict__ T1N,
    u16* __restrict__ T2L, u16* __restrict__ T2N,
    const float* __restrict__ b1L, const float* __restrict__ b1N,
    const float* __restrict__ b2L, const float* __restrict__ b2N,
    float* __restrict__ cb1, float* __restrict__ cb2,
    const float* __restrict__ x, u32* __restrict__ xb, int nx4,
    int nH)
{
    const int t = threadIdx.x;
    const int bid = blockIdx.x;
    if (bid < nH) {
        __shared__ int hist[2][64];
        if (t < 64) { hist[0][t] = 0; hist[1][t] = 0; }
        __syncthreads();
        const int b0 = bid * HCHUNK;
        {
            const int4* c4 = (const int4*)colL;
            int b1e = min(b0 + HCHUNK, eL >> 2);
            for (int i = b0 + t; i < b1e; i += 256) {
                int4 c = c4[i];
                atomicAdd(&hist[0][c.x >> BSHIFT], 1);
                atomicAdd(&hist[0][c.y >> BSHIFT], 1);
                atomicAdd(&hist[0][c.z >> BSHIFT], 1);
                atomicAdd(&hist[0][c.w >> BSHIFT], 1);
            }
            const int4* d4 = (const int4*)colN;
            int b1f = min(b0 + HCHUNK, eN >> 2);
            for (int i = b0 + t; i < b1f; i += 256) {
                int4 c = d4[i];
                atomicAdd(&hist[1][c.x >> BSHIFT], 1);
                atomicAdd(&hist[1][c.y >> BSHIFT], 1);
                atomicAdd(&hist[1][c.z >> BSHIFT], 1);
                atomicAdd(&hist[1][c.w >> BSHIFT], 1);
            }
            if (bid == 0) {
                if (t < (eL & 3)) atomicAdd(&hist[0][colL[(eL & ~3) + t] >> BSHIFT], 1);
                if (t < (eN & 3)) atomicAdd(&hist[1][colN[(eN & ~3) + t] >> BSHIFT], 1);
            }
        }
        __syncthreads();
        if (t < 64) {
            if (hist[0][t]) atomicAdd(&bcnt[t], hist[0][t]);
            if (hist[1][t]) atomicAdd(&bcnt[64 + t], hist[1][t]);
        }
    } else if (bid < nH + 256) {
        int b = bid - nH;
        int which = b >> 6, bx = b & 63;
        const float* src = which == 0 ? W1L : which == 1 ? W1N : which == 2 ? W2L : W2N;
        u16* dst         = which == 0 ? T1L : which == 1 ? T1N : which == 2 ? T2L : T2N;
        const int nc = which < 2 ? 128 : 64;
        int i = bx * 256 + t;
        if (i < 128 * nc) {
            int k = i / nc, nn = i % nc;
            dst[nn * 128 + k] = bf16_rne1(src[i]);
        }
    } else if (bid == nH + 256) {
        if (t < 128) cb1[t] = b1L[t] + 0.5f * b1N[t];
        if (t < 64)  cb2[t] = b2L[t] + 0.5f * b2N[t];
    } else {
        int i4 = (bid - nH - 257) * 256 + t;
        if (i4 < nx4) {
            float4 v = ((const float4*)x)[i4];
            ((uint2*)xb)[i4] = make_uint2(pack_bf16_rne(v.x, v.y),
                                          pack_bf16_rne(v.z, v.w));
        }
    }
}

// -------- scanB2: bucket bases -> gcur (binA reservation), bbase, rowptr[n] --------

__global__ __launch_bounds__(64) void scanB2_kernel(
    const int* __restrict__ bcnt, int nb,
    int* __restrict__ gcurL, int* __restrict__ gcurN,
    int* __restrict__ bbase,
    int* __restrict__ rowptrL, int* __restrict__ rowptrN, int n)
{
    const int l = threadIdx.x;
    #pragma unroll
    for (int adj = 0; adj < 2; ++adj) {
        int v = (l < nb) ? bcnt[adj * 64 + l] : 0;
        int orig = v;
        for (int off = 1; off < 64; off <<= 1) {
            int u = __shfl_up(v, off, 64);
            if (l >= off) v += u;
        }
        int excl = v - orig;
        if (l < nb) {
            int* gcur = adj ? gcurN : gcurL;
            gcur[l] = excl;
            bbase[adj * 65 + l] = excl;
        }
        if (l == 63) {
            bbase[adj * 65 + nb] = v;
            int* rowptr = adj ? rowptrN : rowptrL;
            rowptr[n] = v;
        }
    }
}

// -------- binA: reservation staging (packed (row<<11)|local-col) --------

__global__ __launch_bounds__(256) void binA_kernel(
    const int* __restrict__ rowL, const int* __restrict__ colL, int eL,
    const int* __restrict__ rowN, const int* __restrict__ colN, int eN,
    int* __restrict__ gcurL, int* __restrict__ gcurN,
    u32* __restrict__ stagedL, u32* __restrict__ stagedN, int nb, int nA)
{
    __shared__ int hist[64];
    __shared__ int base[64];
    const int t = threadIdx.x;
    const int adj = (int)blockIdx.x >= nA;
    const int chunkb = adj ? blockIdx.x - nA : blockIdx.x;
    const int* rowA = adj ? rowN : rowL;
    const int* colA = adj ? colN : colL;
    const int e     = adj ? eN   : eL;
    int* gcur       = adj ? gcurN : gcurL;
    u32* staged     = adj ? stagedN : stagedL;

    if (t < 64) hist[t] = 0;
    __syncthreads();

    const int i0 = chunkb * ACHUNK;
    const int i1 = min(i0 + ACHUNK, e);

    for (int i = i0 + t; i < i1; i += 256)
        atomicAdd(&hist[colA[i] >> BSHIFT], 1);
    __syncthreads();

    if (t < 64) {
        int cnt = hist[t];
        if (t < nb && cnt > 0) base[t] = atomicAdd(&gcur[t], cnt);
    }
    __syncthreads();
    if (t < 64) hist[t] = 0;
    __syncthreads();

    for (int i = i0 + t; i < i1; i += 256) {
        int c = colA[i], r = rowA[i];
        int b = c >> BSHIFT;
        int pos = base[b] + atomicAdd(&hist[b], 1);
        staged[pos] = ((u32)r << BSHIFT) | ((u32)c & (BW - 1));
    }
}

// -------- binB2: per-node count + in-LDS scan -> rowptr, dinv, csr --------

__global__ __launch_bounds__(256) void binB2_kernel(
    const int* __restrict__ bbase,
    const u32* __restrict__ stagedL, const u32* __restrict__ stagedN,
    int* __restrict__ rowptrL, int* __restrict__ rowptrN,
    float* __restrict__ dinvL, float* __restrict__ dinvN,
    int* __restrict__ csrL, int* __restrict__ csrN, int n)
{
    const int adj = blockIdx.y;
    const u32* staged = adj ? stagedN : stagedL;
    int* rowptr       = adj ? rowptrN : rowptrL;
    float* dinv       = adj ? dinvN : dinvL;
    int* csr          = adj ? csrN  : csrL;

    __shared__ int lcnt[BW];
    __shared__ int sh[256];
    const int b = blockIdx.x;
    const int lo = b << BSHIFT;
    const int hi = min(lo + BW, n);
    const int t = threadIdx.x;
    const int base = bbase[adj * 65 + b];
    const int end  = bbase[adj * 65 + b + 1];

    #pragma unroll
    for (int j = t; j < BW; j += 256) lcnt[j] = 0;
    __syncthreads();

    for (int i = base + t; i < end; i += 256)
        atomicAdd(&lcnt[staged[i] & (BW - 1)], 1);
    __syncthreads();

    int c[8]; int s = 0;
    #pragma unroll
    for (int j = 0; j < 8; ++j) { c[j] = lcnt[t * 8 + j]; s += c[j]; }
    sh[t] = s;
    __syncthreads();
    for (int off = 1; off < 256; off <<= 1) {
        int a = (t >= off) ? sh[t - off] : 0;
        __syncthreads();
        sh[t] += a;
        __syncthreads();
    }
    int run = base + sh[t] - s;    // exclusive prefix within bucket
    #pragma unroll
    for (int j = 0; j < 8; ++j) {
        int idx = lo + t * 8 + j;
        if (idx < hi) {
            rowptr[idx] = run;
            dinv[idx] = rsqrtf((float)c[j] + 1.0f);   // +1 self loop
        }
        lcnt[t * 8 + j] = run;     // cursor for placement
        run += c[j];
    }
    __syncthreads();

    for (int i = base + t; i < end; i += 256) {
        u32 v = staged[i];
        int p = atomicAdd(&lcnt[v & (BW - 1)], 1);
        csr[p] = (int)(v >> BSHIFT);
    }
}

// ---------------- fused gather + combine-GEMM (unchanged from R14) ----------------

template<int NCH, bool STATS>
__global__ __launch_bounds__(512) void fused_gg_kernel(
    const int* __restrict__ rowptrL, const int* __restrict__ csrL,
    const int* __restrict__ rowptrN, const int* __restrict__ csrN,
    const u32* __restrict__ src,
    const u16* __restrict__ WtL, const u16* __restrict__ WtN,
    const float* __restrict__ dinvL, const float* __restrict__ dinvN,
    const float* __restrict__ cb, void* __restrict__ outp, int n,
    float* __restrict__ bn_sum, float* __restrict__ bn_sumsq)
{
    constexpr int NTN = (NCH == 128) ? 4 : 2;   // node-tiles per wave
    __shared__ u16 ls[2][64 * 128];
    __shared__ float bns[128], bnq[128];

    const int t = threadIdx.x;
    const int l = t & 63, w = t >> 6;
    const int row0 = blockIdx.x * 64;
    if (STATS && t < 128) { bns[t] = 0.f; bnq[t] = 0.f; }

    // ---- gather phase: wave w -> rows w*8 .. w*8+7
    for (int i = 0; i < 8; ++i) {
        const int r = w * 8 + i;
        const int node = row0 + r;
        u32 packL = 0, packN = 0;
        if (node < n) {
            u32 xv = src[(size_t)node * 64 + l];
            float dlv = dinvL[node], dnv = dinvN[node];
            float sL0 = dlv * bf16_lo(xv), sL1 = dlv * bf16_hi(xv);
            float sN0 = dnv * bf16_lo(xv), sN1 = dnv * bf16_hi(xv);

            int jL  = __builtin_amdgcn_readfirstlane(rowptrL[node]);
            int e2L = __builtin_amdgcn_readfirstlane(rowptrL[node + 1]);
            int jN  = __builtin_amdgcn_readfirstlane(rowptrN[node]);
            int e2N = __builtin_amdgcn_readfirstlane(rowptrN[node + 1]);
            const int lenL = e2L - jL;
            const int lenN = e2N - jN;

            int idxL[8], idxN[8];
            if (lenL > 0) {
                #pragma unroll
                for (int k = 0; k < 8; ++k) idxL[k] = csrL[jL + min(k, lenL - 1)];
            }
            if (lenN > 0) {
                #pragma unroll
                for (int k = 0; k < 8; ++k) idxN[k] = csrN[jN + min(k, lenN - 1)];
            }

            const int mx = max(lenL, lenN);
            for (int base = 0; base < mx; base += 8) {
                const bool doL = base < lenL;
                const bool doN = base < lenN;
                u32 aL[8], aN[8];
                float dl[8], dn[8];
                if (doL) {
                    #pragma unroll
                    for (int k = 0; k < 8; ++k) aL[k] = src[(size_t)idxL[k] * 64 + l];
                    #pragma unroll
                    for (int k = 0; k < 8; ++k) {
                        float d = dinvL[idxL[k]];
                        dl[k] = (base + k < lenL) ? d : 0.f;
                    }
                }
                if (doN) {
                    #pragma unroll
                    for (int k = 0; k < 8; ++k) aN[k] = src[(size_t)idxN[k] * 64 + l];
                    #pragma unroll
                    for (int k = 0; k < 8; ++k) {
                        float d = dinvN[idxN[k]];
                        dn[k] = (base + k < lenN) ? d : 0.f;
                    }
                }
                if (doL && base + 8 < lenL) {
                    #pragma unroll
                    for (int k = 0; k < 8; ++k) idxL[k] = csrL[jL + min(base + 8 + k, lenL - 1)];
                }
                if (doN && base + 8 < lenN) {
                    #pragma unroll
                    for (int k = 0; k < 8; ++k) idxN[k] = csrN[jN + min(base + 8 + k, lenN - 1)];
                }
                if (doL) {
                    #pragma unroll
                    for (int k = 0; k < 8; ++k) {
                        sL0 = fmaf(dl[k], bf16_lo(aL[k]), sL0);
                        sL1 = fmaf(dl[k], bf16_hi(aL[k]), sL1);
                    }
                }
                if (doN) {
                    #pragma unroll
                    for (int k = 0; k < 8; ++k) {
                        sN0 = fmaf(dn[k], bf16_lo(aN[k]), sN0);
                        sN1 = fmaf(dn[k], bf16_hi(aN[k]), sN1);
                    }
                }
            }
            packL = pack_bf16_rne(sL0, sL1);
            packN = pack_bf16_rne(sN0, sN1);
        }
        const int byte = (r * 256 + l * 4) ^ ((r & 7) << 4);
        *(u32*)((char*)&ls[0][0] + byte) = packL;
        *(u32*)((char*)&ls[1][0] + byte) = packN;
    }
    __syncthreads();

    // ---- MFMA phase
    const int lm = l & 15, lq = l >> 4;
    const int chbase = (NCH == 128) ? w * 16 : (w & 3) * 16;
    const int nt0    = (NCH == 128) ? 0 : (w >> 2) * 2;

    f32x4 accL[NTN], accN[NTN];
    #pragma unroll
    for (int q = 0; q < NTN; ++q) {
        accL[q] = (f32x4){0.f, 0.f, 0.f, 0.f};
        accN[q] = (f32x4){0.f, 0.f, 0.f, 0.f};
    }

    #pragma unroll
    for (int ks = 0; ks < 4; ++ks) {
        const int k0 = ks * 32 + lq * 8;
        bf16x8 wfL = *(const bf16x8*)&WtL[(size_t)(chbase + lm) * 128 + k0];
        bf16x8 wfN = *(const bf16x8*)&WtN[(size_t)(chbase + lm) * 128 + k0];
        #pragma unroll
        for (int q = 0; q < NTN; ++q) {
            const int m = (nt0 + q) * 16 + lm;
            const int byte = (m * 256 + k0 * 2) ^ ((m & 7) << 4);
            bf16x8 xL = *(const bf16x8*)((const char*)&ls[0][0] + byte);
            bf16x8 xN = *(const bf16x8*)((const char*)&ls[1][0] + byte);
            accL[q] = __builtin_amdgcn_mfma_f32_16x16x32_bf16(wfL, xL, accL[q], 0, 0, 0);
            accN[q] = __builtin_amdgcn_mfma_f32_16x16x32_bf16(wfN, xN, accN[q], 0, 0, 0);
        }
    }

    // ---- epilogue
    float sv[4] = {0.f, 0.f, 0.f, 0.f}, sq[4] = {0.f, 0.f, 0.f, 0.f};
    const int ch0 = chbase + lq * 4;
    const float4 cbv = *(const float4*)&cb[ch0];

    #pragma unroll
    for (int q = 0; q < NTN; ++q) {
        const int node = row0 + (nt0 + q) * 16 + lm;
        const bool ok = node < n;
        const int nodec = ok ? node : 0;
        float dl = ok ? dinvL[nodec] : 0.f;
        float dn = ok ? 0.5f * dinvN[nodec] : 0.f;
        f32x4 aL = accL[q], aN = accN[q];
        float v0 = dl * aL[0] + dn * aN[0] + cbv.x;
        float v1 = dl * aL[1] + dn * aN[1] + cbv.y;
        float v2 = dl * aL[2] + dn * aN[2] + cbv.z;
        float v3 = dl * aL[3] + dn * aN[3] + cbv.w;
        if constexpr (STATS) {
            if (ok) {
                uint2 pk;
                pk.x = pack_bf16_rne(v0, v1);
                pk.y = pack_bf16_rne(v2, v3);
                *(uint2*)&((u32*)outp)[(size_t)node * 64 + (ch0 >> 1)] = pk;
                sv[0] += v0; sv[1] += v1; sv[2] += v2; sv[3] += v3;
                sq[0] += v0 * v0; sq[1] += v1 * v1; sq[2] += v2 * v2; sq[3] += v3 * v3;
            }
        } else {
            if (ok)
                *(float4*)&((float*)outp)[(size_t)node * NCH + ch0] =
                    make_float4(v0, v1, v2, v3);
        }
    }

    if constexpr (STATS) {
        #pragma unroll
        for (int r = 0; r < 4; ++r) {
            float a = sv[r], b = sq[r];
            #pragma unroll
            for (int m = 1; m <= 8; m <<= 1) {
                a += __shfl_xor(a, m, 64);
                b += __shfl_xor(b, m, 64);
            }
            if (lm == 0) {
                bns[ch0 + r] = a;
                bnq[ch0 + r] = b;
            }
        }
        __syncthreads();
        if (t < 128) {
            atomicAdd(&bn_sum[t], bns[t]);
            atomicAdd(&bn_sumsq[t], bnq[t]);
        }
    }
}

// ---------------- BN finalize + ReLU + bf16 quant: h -> hb ----------------

__global__ __launch_bounds__(256) void bnquant_kernel(
    const u32* __restrict__ h, u32* __restrict__ hb,
    const float* __restrict__ bn_sum, const float* __restrict__ bn_sumsq,
    const float* __restrict__ gamma, const float* __restrict__ beta,
    float inv_n, int total)                     // total = n*64 u32s
{
    __shared__ float sc_s[128], sh_s[128];
    const int t = threadIdx.x;
    if (t < 128) {
        float mean = bn_sum[t] * inv_n;
        float var  = bn_sumsq[t] * inv_n - mean * mean;
        float sc = gamma[t] * rsqrtf(var + 1e-5f);
        sc_s[t] = sc;
        sh_s[t] = beta[t] - mean * sc;
    }
    __syncthreads();

    int i0 = (blockIdx.x * 256 + t) * 4;
    if (i0 + 4 <= total) {
        uint4 v = *(const uint4*)&h[i0];
        u32 r[4];
        u32 vv[4] = {v.x, v.y, v.z, v.w};
        #pragma unroll
        for (int j = 0; j < 4; ++j) {
            int cp = (i0 + j) & 63;
            float a = fmaxf(bf16_lo(vv[j]) * sc_s[2 * cp]     + sh_s[2 * cp],     0.f);
            float b = fmaxf(bf16_hi(vv[j]) * sc_s[2 * cp + 1] + sh_s[2 * cp + 1], 0.f);
            r[j] = pack_bf16_rne(a, b);
        }
        *(uint4*)&hb[i0] = make_uint4(r[0], r[1], r[2], r[3]);
    } else {
        for (int i = i0; i < total; ++i) {
            int cp = i & 63;
            u32 u = h[i];
            float a = fmaxf(bf16_lo(u) * sc_s[2 * cp]     + sh_s[2 * cp],     0.f);
            float b = fmaxf(bf16_hi(u) * sc_s[2 * cp + 1] + sh_s[2 * cp + 1], 0.f);
            hb[i] = pack_bf16_rne(a, b);
        }
    }
}

// ---------------- launch ----------------

extern "C" void kernel_launch(void* const* d_in, const int* in_sizes, int n_in,
                              void* d_out, int out_size, void* d_ws, size_t ws_size,
                              hipStream_t stream)
{
    const float* x     = (const float*)d_in[0];
    const int*   adjL  = (const int*)d_in[1];   // adj_low
    const int*   adjN  = (const int*)d_in[3];   // adj_nd_low
    const float* W1L   = (const float*)d_in[5];
    const float* b1L   = (const float*)d_in[6];
    const float* W1N   = (const float*)d_in[7];
    const float* b1N   = (const float*)d_in[8];
    const float* gamma = (const float*)d_in[9];
    const float* beta  = (const float*)d_in[10];
    const float* W2L   = (const float*)d_in[11];
    const float* b2L   = (const float*)d_in[12];
    const float* W2N   = (const float*)d_in[13];
    const float* b2N   = (const float*)d_in[14];

    const int n  = in_sizes[0] / 128;
    const int eL = in_sizes[1] / 2;
    const int eN = in_sizes[3] / 2;
    const int* rowL = adjL;  const int* colL = adjL + eL;
    const int* rowN = adjN;  const int* colN = adjN + eN;
    const int nb = idiv_up(n, BW);      // buckets, <= 64

    char* p = (char*)d_ws;
    const size_t tb = (size_t)n * 128 * sizeof(u16);    // bf16 [n][128] table
    u32* xb = (u32*)p; p += tb;         // x bf16; later aliased by hb
    u32* h  = (u32*)p; p += tb;         // h bf16; earlier aliased by staged
    float* dinvL = (float*)p; p += (size_t)n * sizeof(float);
    float* dinvN = (float*)p; p += (size_t)n * sizeof(float);
    float* bn_sum   = (float*)p; p += 128 * sizeof(float);
    float* bn_sumsq = (float*)p; p += 128 * sizeof(float);
    float* cb1 = (float*)p; p += 128 * sizeof(float);
    float* cb2 = (float*)p; p += 64 * sizeof(float);
    int* rowptrL = (int*)p; p += (size_t)(n + 1) * sizeof(int);
    int* rowptrN = (int*)p; p += (size_t)(n + 1) * sizeof(int);
    int* gcurL   = (int*)p; p += 64 * sizeof(int);
    int* gcurN   = (int*)p; p += 64 * sizeof(int);
    int* bcnt    = (int*)p; p += 128 * sizeof(int);
    int* bbase   = (int*)p; p += 130 * sizeof(int);
    int* csrL    = (int*)p; p += (size_t)eL * sizeof(int);
    int* csrN    = (int*)p; p += (size_t)eN * sizeof(int);
    u16* WtL1 = (u16*)p; p += 128 * 128 * sizeof(u16);
    u16* WtN1 = (u16*)p; p += 128 * 128 * sizeof(u16);
    u16* WtL2 = (u16*)p; p += 64 * 128 * sizeof(u16);
    u16* WtN2 = (u16*)p; p += 64 * 128 * sizeof(u16);

    // staged (eL+eN u32 = 12.8 MB) aliases h (25.6 MB): staged dead after
    // binB2; h written first by fused_gg<128> (after binB2). Stream-ordered.
    u32* stagedL = (u32*)h;
    u32* stagedN = stagedL + eL;
    // hb aliases xb: xb dead after fused_gg<128>'s gather; hb written by
    // bnquant afterwards.
    u32* hb = xb;

    hipMemsetAsync(bcnt, 0, 128 * sizeof(int), stream);
    hipMemsetAsync(bn_sum, 0, 2 * 128 * sizeof(float), stream);

    const int emax = eL > eN ? eL : eN;

    // 1. bucket-hist ∥ wprep ∥ combined-bias ∥ x->bf16
    const int nH = idiv_up(emax >> 2, HCHUNK);
    const int nx4 = n * 32;
    const int nxq = idiv_up(nx4, 256);
    prep2_kernel<<<nH + 257 + nxq, 256, 0, stream>>>(
        colL, colN, eL, eN, bcnt,
        W1L, W1N, W2L, W2N, WtL1, WtN1, WtL2, WtN2,
        b1L, b1N, b2L, b2N, cb1, cb2,
        x, xb, nx4, nH);

    // 2. bucket bases
    scanB2_kernel<<<1, 64, 0, stream>>>(bcnt, nb, gcurL, gcurN, bbase,
                                        rowptrL, rowptrN, n);

    // 3. binA: stage bucket-sorted packed edges
    const int nA = idiv_up(emax, ACHUNK);
    binA_kernel<<<2 * nA, 256, 0, stream>>>(
        rowL, colL, eL, rowN, colN, eN, gcurL, gcurN, stagedL, stagedN, nb, nA);

    // 4. binB2: per-node count/scan -> rowptr, dinv, csr
    binB2_kernel<<<dim3(nb, 2), 256, 0, stream>>>(
        bbase, stagedL, stagedN, rowptrL, rowptrN, dinvL, dinvN, csrL, csrN, n);

    // 5. layer-1 fused gather+GEMM (+BN stats) -> h bf16
    fused_gg_kernel<128, true><<<idiv_up(n, 64), 512, 0, stream>>>(
        rowptrL, csrL, rowptrN, csrN, xb, WtL1, WtN1, dinvL, dinvN,
        cb1, h, n, bn_sum, bn_sumsq);

    // 6. BN finalize + ReLU + quant -> hb
    bnquant_kernel<<<idiv_up(n * 64, 1024), 256, 0, stream>>>(
        h, hb, bn_sum, bn_sumsq, gamma, beta, 1.0f / (float)n, n * 64);

    // 7. layer-2 fused gather+GEMM -> d_out fp32
    fused_gg_kernel<64, false><<<idiv_up(n, 64), 512, 0, stream>>>(
        rowptrL, csrL, rowptrN, csrN, hb, WtL2, WtN2, dinvL, dinvN,
        cb2, d_out, n, nullptr, nullptr);
}

// Round 16
// 436.243 us; speedup vs baseline: 1.8345x; 1.0850x over previous
//
#include <hip/hip_runtime.h>

typedef unsigned int u32;
typedef unsigned short u16;
using bf16x8 = __attribute__((ext_vector_type(8))) short;
using f32x4  = __attribute__((ext_vector_type(4))) float;

static inline int idiv_up(int a, int b) { return (a + b - 1) / b; }

#define BSHIFT 9           // bucket width 512 nodes
#define BW     512
#define NBMAX  256         // max buckets (n < 131072)
#define ACHUNK 16384       // edges per binA block
#define HCHUNK 4096        // int4s per hist block

// ---------------- bf16 pack/unpack ----------------

__device__ __forceinline__ u32 pack_bf16_rne(float lo, float hi) {
    u32 ul = __float_as_uint(lo);
    u32 uh = __float_as_uint(hi);
    ul = (ul + 0x7fffu + ((ul >> 16) & 1u)) >> 16;
    uh = (uh + 0x7fffu + ((uh >> 16) & 1u));
    return (ul & 0xffffu) | (uh & 0xffff0000u);
}
__device__ __forceinline__ u16 bf16_rne1(float v) {
    u32 u = __float_as_uint(v);
    return (u16)((u + 0x7fffu + ((u >> 16) & 1u)) >> 16);
}
__device__ __forceinline__ float bf16_lo(u32 u) { return __uint_as_float(u << 16); }
__device__ __forceinline__ float bf16_hi(u32 u) { return __uint_as_float(u & 0xffff0000u); }

// -------- prep2: bucket-hist ∥ wprep ∥ combined-bias ∥ x->bf16 --------

__global__ __launch_bounds__(256) void prep2_kernel(
    const int* __restrict__ colL, const int* __restrict__ colN,
    int eL, int eN, int* __restrict__ bcnt,
    const float* __restrict__ W1L, const float* __restrict__ W1N,
    const float* __restrict__ W2L, const float* __restrict__ W2N,
    u16* __restrict__ T1L, u16* __restrict__ T1N,
    u16* __restrict__ T2L, u16* __restrict__ T2N,
    const float* __restrict__ b1L, const float* __restrict__ b1N,
    const float* __restrict__ b2L, const float* __restrict__ b2N,
    float* __restrict__ cb1, float* __restrict__ cb2,
    const float* __restrict__ x, u32* __restrict__ xb, int nx4,
    int nH)
{
    const int t = threadIdx.x;
    const int bid = blockIdx.x;
    if (bid < nH) {
        __shared__ int hist[2][NBMAX];
        hist[0][t] = 0; hist[1][t] = 0;
        __syncthreads();
        const int b0 = bid * HCHUNK;
        {
            const int4* c4 = (const int4*)colL;
            int b1e = min(b0 + HCHUNK, eL >> 2);
            for (int i = b0 + t; i < b1e; i += 256) {
                int4 c = c4[i];
                atomicAdd(&hist[0][c.x >> BSHIFT], 1);
                atomicAdd(&hist[0][c.y >> BSHIFT], 1);
                atomicAdd(&hist[0][c.z >> BSHIFT], 1);
                atomicAdd(&hist[0][c.w >> BSHIFT], 1);
            }
            const int4* d4 = (const int4*)colN;
            int b1f = min(b0 + HCHUNK, eN >> 2);
            for (int i = b0 + t; i < b1f; i += 256) {
                int4 c = d4[i];
                atomicAdd(&hist[1][c.x >> BSHIFT], 1);
                atomicAdd(&hist[1][c.y >> BSHIFT], 1);
                atomicAdd(&hist[1][c.z >> BSHIFT], 1);
                atomicAdd(&hist[1][c.w >> BSHIFT], 1);
            }
            if (bid == 0) {
                if (t < (eL & 3)) atomicAdd(&hist[0][colL[(eL & ~3) + t] >> BSHIFT], 1);
                if (t < (eN & 3)) atomicAdd(&hist[1][colN[(eN & ~3) + t] >> BSHIFT], 1);
            }
        }
        __syncthreads();
        if (hist[0][t]) atomicAdd(&bcnt[t], hist[0][t]);
        if (hist[1][t]) atomicAdd(&bcnt[NBMAX + t], hist[1][t]);
    } else if (bid < nH + 256) {
        int b = bid - nH;
        int which = b >> 6, bx = b & 63;
        const float* src = which == 0 ? W1L : which == 1 ? W1N : which == 2 ? W2L : W2N;
        u16* dst         = which == 0 ? T1L : which == 1 ? T1N : which == 2 ? T2L : T2N;
        const int nc = which < 2 ? 128 : 64;
        int i = bx * 256 + t;
        if (i < 128 * nc) {
            int k = i / nc, nn = i % nc;
            dst[nn * 128 + k] = bf16_rne1(src[i]);
        }
    } else if (bid == nH + 256) {
        if (t < 128) cb1[t] = b1L[t] + 0.5f * b1N[t];
        if (t < 64)  cb2[t] = b2L[t] + 0.5f * b2N[t];
    } else {
        int i4 = (bid - nH - 257) * 256 + t;
        if (i4 < nx4) {
            float4 v = ((const float4*)x)[i4];
            ((uint2*)xb)[i4] = make_uint2(pack_bf16_rne(v.x, v.y),
                                          pack_bf16_rne(v.z, v.w));
        }
    }
}

// -------- scanB2: bucket bases -> gcur (binA reservation), bbase, rowptr[n] --------

__global__ __launch_bounds__(256) void scanB2_kernel(
    const int* __restrict__ bcnt, int nb,
    int* __restrict__ gcurL, int* __restrict__ gcurN,
    int* __restrict__ bbase,
    int* __restrict__ rowptrL, int* __restrict__ rowptrN, int n)
{
    __shared__ int sh[256];
    const int t = threadIdx.x;
    #pragma unroll
    for (int adj = 0; adj < 2; ++adj) {
        int v = (t < nb) ? bcnt[adj * NBMAX + t] : 0;
        sh[t] = v;
        __syncthreads();
        for (int off = 1; off < 256; off <<= 1) {
            int a = (t >= off) ? sh[t - off] : 0;
            __syncthreads();
            sh[t] += a;
            __syncthreads();
        }
        int excl = sh[t] - v;
        if (t < nb) {
            int* gcur = adj ? gcurN : gcurL;
            gcur[t] = excl;
            bbase[adj * (NBMAX + 1) + t] = excl;
        }
        if (t == 255) {
            bbase[adj * (NBMAX + 1) + nb] = sh[255];
            int* rowptr = adj ? rowptrN : rowptrL;
            rowptr[n] = sh[255];
        }
        __syncthreads();
    }
}

// -------- binA: reservation staging (packed (row<<9)|local-col) --------

__global__ __launch_bounds__(256) void binA_kernel(
    const int* __restrict__ rowL, const int* __restrict__ colL, int eL,
    const int* __restrict__ rowN, const int* __restrict__ colN, int eN,
    int* __restrict__ gcurL, int* __restrict__ gcurN,
    u32* __restrict__ stagedL, u32* __restrict__ stagedN, int nb, int nA)
{
    __shared__ int hist[NBMAX];
    __shared__ int base[NBMAX];
    const int t = threadIdx.x;
    const int adj = (int)blockIdx.x >= nA;
    const int chunkb = adj ? blockIdx.x - nA : blockIdx.x;
    const int* rowA = adj ? rowN : rowL;
    const int* colA = adj ? colN : colL;
    const int e     = adj ? eN   : eL;
    int* gcur       = adj ? gcurN : gcurL;
    u32* staged     = adj ? stagedN : stagedL;

    hist[t] = 0;
    __syncthreads();

    const int i0 = chunkb * ACHUNK;
    const int i1 = min(i0 + ACHUNK, e);

    for (int i = i0 + t; i < i1; i += 256)
        atomicAdd(&hist[colA[i] >> BSHIFT], 1);
    __syncthreads();

    {
        int cnt = hist[t];
        if (t < nb && cnt > 0) base[t] = atomicAdd(&gcur[t], cnt);
    }
    __syncthreads();
    hist[t] = 0;
    __syncthreads();

    for (int i = i0 + t; i < i1; i += 256) {
        int c = colA[i], r = rowA[i];
        int b = c >> BSHIFT;
        int pos = base[b] + atomicAdd(&hist[b], 1);
        staged[pos] = ((u32)r << BSHIFT) | ((u32)c & (BW - 1));
    }
}

// -------- binB2: per-node count + in-LDS scan -> rowptr, dinv, csr --------

__global__ __launch_bounds__(256) void binB2_kernel(
    const int* __restrict__ bbase,
    const u32* __restrict__ stagedL, const u32* __restrict__ stagedN,
    int* __restrict__ rowptrL, int* __restrict__ rowptrN,
    float* __restrict__ dinvL, float* __restrict__ dinvN,
    int* __restrict__ csrL, int* __restrict__ csrN, int n)
{
    const int adj = blockIdx.y;
    const u32* staged = adj ? stagedN : stagedL;
    int* rowptr       = adj ? rowptrN : rowptrL;
    float* dinv       = adj ? dinvN : dinvL;
    int* csr          = adj ? csrN  : csrL;

    __shared__ int lcnt[BW];
    __shared__ int sh[256];
    const int b = blockIdx.x;
    const int lo = b << BSHIFT;
    const int hi = min(lo + BW, n);
    const int t = threadIdx.x;
    const int base = bbase[adj * (NBMAX + 1) + b];
    const int end  = bbase[adj * (NBMAX + 1) + b + 1];

    #pragma unroll
    for (int j = t; j < BW; j += 256) lcnt[j] = 0;
    __syncthreads();

    for (int i = base + t; i < end; i += 256)
        atomicAdd(&lcnt[staged[i] & (BW - 1)], 1);
    __syncthreads();

    int c[2]; int s = 0;
    #pragma unroll
    for (int j = 0; j < 2; ++j) { c[j] = lcnt[t * 2 + j]; s += c[j]; }
    sh[t] = s;
    __syncthreads();
    for (int off = 1; off < 256; off <<= 1) {
        int a = (t >= off) ? sh[t - off] : 0;
        __syncthreads();
        sh[t] += a;
        __syncthreads();
    }
    int run = base + sh[t] - s;    // exclusive prefix within bucket
    #pragma unroll
    for (int j = 0; j < 2; ++j) {
        int idx = lo + t * 2 + j;
        if (idx < hi) {
            rowptr[idx] = run;
            dinv[idx] = rsqrtf((float)c[j] + 1.0f);   // +1 self loop
        }
        lcnt[t * 2 + j] = run;     // cursor for placement
        run += c[j];
    }
    __syncthreads();

    for (int i = base + t; i < end; i += 256) {
        u32 v = staged[i];
        int p = atomicAdd(&lcnt[v & (BW - 1)], 1);
        csr[p] = (int)(v >> BSHIFT);
    }
}

// ---------------- fused gather + combine-GEMM (unchanged) ----------------

template<int NCH, bool STATS>
__global__ __launch_bounds__(512) void fused_gg_kernel(
    const int* __restrict__ rowptrL, const int* __restrict__ csrL,
    const int* __restrict__ rowptrN, const int* __restrict__ csrN,
    const u32* __restrict__ src,
    const u16* __restrict__ WtL, const u16* __restrict__ WtN,
    const float* __restrict__ dinvL, const float* __restrict__ dinvN,
    const float* __restrict__ cb, void* __restrict__ outp, int n,
    float* __restrict__ bn_sum, float* __restrict__ bn_sumsq)
{
    constexpr int NTN = (NCH == 128) ? 4 : 2;   // node-tiles per wave
    __shared__ u16 ls[2][64 * 128];
    __shared__ float bns[128], bnq[128];

    const int t = threadIdx.x;
    const int l = t & 63, w = t >> 6;
    const int row0 = blockIdx.x * 64;
    if (STATS && t < 128) { bns[t] = 0.f; bnq[t] = 0.f; }

    // ---- gather phase: wave w -> rows w*8 .. w*8+7
    for (int i = 0; i < 8; ++i) {
        const int r = w * 8 + i;
        const int node = row0 + r;
        u32 packL = 0, packN = 0;
        if (node < n) {
            u32 xv = src[(size_t)node * 64 + l];
            float dlv = dinvL[node], dnv = dinvN[node];
            float sL0 = dlv * bf16_lo(xv), sL1 = dlv * bf16_hi(xv);
            float sN0 = dnv * bf16_lo(xv), sN1 = dnv * bf16_hi(xv);

            int jL  = __builtin_amdgcn_readfirstlane(rowptrL[node]);
            int e2L = __builtin_amdgcn_readfirstlane(rowptrL[node + 1]);
            int jN  = __builtin_amdgcn_readfirstlane(rowptrN[node]);
            int e2N = __builtin_amdgcn_readfirstlane(rowptrN[node + 1]);
            const int lenL = e2L - jL;
            const int lenN = e2N - jN;

            int idxL[8], idxN[8];
            if (lenL > 0) {
                #pragma unroll
                for (int k = 0; k < 8; ++k) idxL[k] = csrL[jL + min(k, lenL - 1)];
            }
            if (lenN > 0) {
                #pragma unroll
                for (int k = 0; k < 8; ++k) idxN[k] = csrN[jN + min(k, lenN - 1)];
            }

            const int mx = max(lenL, lenN);
            for (int base = 0; base < mx; base += 8) {
                const bool doL = base < lenL;
                const bool doN = base < lenN;
                u32 aL[8], aN[8];
                float dl[8], dn[8];
                if (doL) {
                    #pragma unroll
                    for (int k = 0; k < 8; ++k) aL[k] = src[(size_t)idxL[k] * 64 + l];
                    #pragma unroll
                    for (int k = 0; k < 8; ++k) {
                        float d = dinvL[idxL[k]];
                        dl[k] = (base + k < lenL) ? d : 0.f;
                    }
                }
                if (doN) {
                    #pragma unroll
                    for (int k = 0; k < 8; ++k) aN[k] = src[(size_t)idxN[k] * 64 + l];
                    #pragma unroll
                    for (int k = 0; k < 8; ++k) {
                        float d = dinvN[idxN[k]];
                        dn[k] = (base + k < lenN) ? d : 0.f;
                    }
                }
                if (doL && base + 8 < lenL) {
                    #pragma unroll
                    for (int k = 0; k < 8; ++k) idxL[k] = csrL[jL + min(base + 8 + k, lenL - 1)];
                }
                if (doN && base + 8 < lenN) {
                    #pragma unroll
                    for (int k = 0; k < 8; ++k) idxN[k] = csrN[jN + min(base + 8 + k, lenN - 1)];
                }
                if (doL) {
                    #pragma unroll
                    for (int k = 0; k < 8; ++k) {
                        sL0 = fmaf(dl[k], bf16_lo(aL[k]), sL0);
                        sL1 = fmaf(dl[k], bf16_hi(aL[k]), sL1);
                    }
                }
                if (doN) {
                    #pragma unroll
                    for (int k = 0; k < 8; ++k) {
                        sN0 = fmaf(dn[k], bf16_lo(aN[k]), sN0);
                        sN1 = fmaf(dn[k], bf16_hi(aN[k]), sN1);
                    }
                }
            }
            packL = pack_bf16_rne(sL0, sL1);
            packN = pack_bf16_rne(sN0, sN1);
        }
        const int byte = (r * 256 + l * 4) ^ ((r & 7) << 4);
        *(u32*)((char*)&ls[0][0] + byte) = packL;
        *(u32*)((char*)&ls[1][0] + byte) = packN;
    }
    __syncthreads();

    // ---- MFMA phase
    const int lm = l & 15, lq = l >> 4;
    const int chbase = (NCH == 128) ? w * 16 : (w & 3) * 16;
    const int nt0    = (NCH == 128) ? 0 : (w >> 2) * 2;

    f32x4 accL[NTN], accN[NTN];
    #pragma unroll
    for (int q = 0; q < NTN; ++q) {
        accL[q] = (f32x4){0.f, 0.f, 0.f, 0.f};
        accN[q] = (f32x4){0.f, 0.f, 0.f, 0.f};
    }

    #pragma unroll
    for (int ks = 0; ks < 4; ++ks) {
        const int k0 = ks * 32 + lq * 8;
        bf16x8 wfL = *(const bf16x8*)&WtL[(size_t)(chbase + lm) * 128 + k0];
        bf16x8 wfN = *(const bf16x8*)&WtN[(size_t)(chbase + lm) * 128 + k0];
        #pragma unroll
        for (int q = 0; q < NTN; ++q) {
            const int m = (nt0 + q) * 16 + lm;
            const int byte = (m * 256 + k0 * 2) ^ ((m & 7) << 4);
            bf16x8 xL = *(const bf16x8*)((const char*)&ls[0][0] + byte);
            bf16x8 xN = *(const bf16x8*)((const char*)&ls[1][0] + byte);
            accL[q] = __builtin_amdgcn_mfma_f32_16x16x32_bf16(wfL, xL, accL[q], 0, 0, 0);
            accN[q] = __builtin_amdgcn_mfma_f32_16x16x32_bf16(wfN, xN, accN[q], 0, 0, 0);
        }
    }

    // ---- epilogue
    float sv[4] = {0.f, 0.f, 0.f, 0.f}, sq[4] = {0.f, 0.f, 0.f, 0.f};
    const int ch0 = chbase + lq * 4;
    const float4 cbv = *(const float4*)&cb[ch0];

    #pragma unroll
    for (int q = 0; q < NTN; ++q) {
        const int node = row0 + (nt0 + q) * 16 + lm;
        const bool ok = node < n;
        const int nodec = ok ? node : 0;
        float dl = ok ? dinvL[nodec] : 0.f;
        float dn = ok ? 0.5f * dinvN[nodec] : 0.f;
        f32x4 aL = accL[q], aN = accN[q];
        float v0 = dl * aL[0] + dn * aN[0] + cbv.x;
        float v1 = dl * aL[1] + dn * aN[1] + cbv.y;
        float v2 = dl * aL[2] + dn * aN[2] + cbv.z;
        float v3 = dl * aL[3] + dn * aN[3] + cbv.w;
        if constexpr (STATS) {
            if (ok) {
                uint2 pk;
                pk.x = pack_bf16_rne(v0, v1);
                pk.y = pack_bf16_rne(v2, v3);
                *(uint2*)&((u32*)outp)[(size_t)node * 64 + (ch0 >> 1)] = pk;
                sv[0] += v0; sv[1] += v1; sv[2] += v2; sv[3] += v3;
                sq[0] += v0 * v0; sq[1] += v1 * v1; sq[2] += v2 * v2; sq[3] += v3 * v3;
            }
        } else {
            if (ok)
                *(float4*)&((float*)outp)[(size_t)node * NCH + ch0] =
                    make_float4(v0, v1, v2, v3);
        }
    }

    if constexpr (STATS) {
        #pragma unroll
        for (int r = 0; r < 4; ++r) {
            float a = sv[r], b = sq[r];
            #pragma unroll
            for (int m = 1; m <= 8; m <<= 1) {
                a += __shfl_xor(a, m, 64);
                b += __shfl_xor(b, m, 64);
            }
            if (lm == 0) {
                bns[ch0 + r] = a;
                bnq[ch0 + r] = b;
            }
        }
        __syncthreads();
        if (t < 128) {
            atomicAdd(&bn_sum[t], bns[t]);
            atomicAdd(&bn_sumsq[t], bnq[t]);
        }
    }
}

// ---------------- BN finalize + ReLU + bf16 quant: h -> hb ----------------

__global__ __launch_bounds__(256) void bnquant_kernel(
    const u32* __restrict__ h, u32* __restrict__ hb,
    const float* __restrict__ bn_sum, const float* __restrict__ bn_sumsq,
    const float* __restrict__ gamma, const float* __restrict__ beta,
    float inv_n, int total)                     // total = n*64 u32s
{
    __shared__ float sc_s[128], sh_s[128];
    const int t = threadIdx.x;
    if (t < 128) {
        float mean = bn_sum[t] * inv_n;
        float var  = bn_sumsq[t] * inv_n - mean * mean;
        float sc = gamma[t] * rsqrtf(var + 1e-5f);
        sc_s[t] = sc;
        sh_s[t] = beta[t] - mean * sc;
    }
    __syncthreads();

    int i0 = (blockIdx.x * 256 + t) * 4;
    if (i0 + 4 <= total) {
        uint4 v = *(const uint4*)&h[i0];
        u32 r[4];
        u32 vv[4] = {v.x, v.y, v.z, v.w};
        #pragma unroll
        for (int j = 0; j < 4; ++j) {
            int cp = (i0 + j) & 63;
            float a = fmaxf(bf16_lo(vv[j]) * sc_s[2 * cp]     + sh_s[2 * cp],     0.f);
            float b = fmaxf(bf16_hi(vv[j]) * sc_s[2 * cp + 1] + sh_s[2 * cp + 1], 0.f);
            r[j] = pack_bf16_rne(a, b);
        }
        *(uint4*)&hb[i0] = make_uint4(r[0], r[1], r[2], r[3]);
    } else {
        for (int i = i0; i < total; ++i) {
            int cp = i & 63;
            u32 u = h[i];
            float a = fmaxf(bf16_lo(u) * sc_s[2 * cp]     + sh_s[2 * cp],     0.f);
            float b = fmaxf(bf16_hi(u) * sc_s[2 * cp + 1] + sh_s[2 * cp + 1], 0.f);
            hb[i] = pack_bf16_rne(a, b);
        }
    }
}

// ---------------- launch ----------------

extern "C" void kernel_launch(void* const* d_in, const int* in_sizes, int n_in,
                              void* d_out, int out_size, void* d_ws, size_t ws_size,
                              hipStream_t stream)
{
    const float* x     = (const float*)d_in[0];
    const int*   adjL  = (const int*)d_in[1];   // adj_low
    const int*   adjN  = (const int*)d_in[3];   // adj_nd_low
    const float* W1L   = (const float*)d_in[5];
    const float* b1L   = (const float*)d_in[6];
    const float* W1N   = (const float*)d_in[7];
    const float* b1N   = (const float*)d_in[8];
    const float* gamma = (const float*)d_in[9];
    const float* beta  = (const float*)d_in[10];
    const float* W2L   = (const float*)d_in[11];
    const float* b2L   = (const float*)d_in[12];
    const float* W2N   = (const float*)d_in[13];
    const float* b2N   = (const float*)d_in[14];

    const int n  = in_sizes[0] / 128;
    const int eL = in_sizes[1] / 2;
    const int eN = in_sizes[3] / 2;
    const int* rowL = adjL;  const int* colL = adjL + eL;
    const int* rowN = adjN;  const int* colN = adjN + eN;
    const int nb = idiv_up(n, BW);      // buckets, <= 256

    char* p = (char*)d_ws;
    const size_t tb = (size_t)n * 128 * sizeof(u16);    // bf16 [n][128] table
    u32* xb = (u32*)p; p += tb;         // x bf16; later aliased by hb
    u32* h  = (u32*)p; p += tb;         // h bf16; earlier aliased by staged
    float* dinvL = (float*)p; p += (size_t)n * sizeof(float);
    float* dinvN = (float*)p; p += (size_t)n * sizeof(float);
    float* bn_sum   = (float*)p; p += 128 * sizeof(float);
    float* bn_sumsq = (float*)p; p += 128 * sizeof(float);
    float* cb1 = (float*)p; p += 128 * sizeof(float);
    float* cb2 = (float*)p; p += 64 * sizeof(float);
    int* rowptrL = (int*)p; p += (size_t)(n + 1) * sizeof(int);
    int* rowptrN = (int*)p; p += (size_t)(n + 1) * sizeof(int);
    int* gcurL   = (int*)p; p += NBMAX * sizeof(int);
    int* gcurN   = (int*)p; p += NBMAX * sizeof(int);
    int* bcnt    = (int*)p; p += 2 * NBMAX * sizeof(int);
    int* bbase   = (int*)p; p += 2 * (NBMAX + 1) * sizeof(int);
    int* csrL    = (int*)p; p += (size_t)eL * sizeof(int);
    int* csrN    = (int*)p; p += (size_t)eN * sizeof(int);
    u16* WtL1 = (u16*)p; p += 128 * 128 * sizeof(u16);
    u16* WtN1 = (u16*)p; p += 128 * 128 * sizeof(u16);
    u16* WtL2 = (u16*)p; p += 64 * 128 * sizeof(u16);
    u16* WtN2 = (u16*)p; p += 64 * 128 * sizeof(u16);

    // staged (eL+eN u32 = 12.8 MB) aliases h (25.6 MB): staged dead after
    // binB2; h written first by fused_gg<128> (after binB2). Stream-ordered.
    u32* stagedL = (u32*)h;
    u32* stagedN = stagedL + eL;
    // hb aliases xb: xb dead after fused_gg<128>'s gather; hb written by
    // bnquant afterwards.
    u32* hb = xb;

    hipMemsetAsync(bcnt, 0, 2 * NBMAX * sizeof(int), stream);
    hipMemsetAsync(bn_sum, 0, 2 * 128 * sizeof(float), stream);

    const int emax = eL > eN ? eL : eN;

    // 1. bucket-hist ∥ wprep ∥ combined-bias ∥ x->bf16
    const int nH = idiv_up(emax >> 2, HCHUNK);
    const int nx4 = n * 32;
    const int nxq = idiv_up(nx4, 256);
    prep2_kernel<<<nH + 257 + nxq, 256, 0, stream>>>(
        colL, colN, eL, eN, bcnt,
        W1L, W1N, W2L, W2N, WtL1, WtN1, WtL2, WtN2,
        b1L, b1N, b2L, b2N, cb1, cb2,
        x, xb, nx4, nH);

    // 2. bucket bases
    scanB2_kernel<<<1, 256, 0, stream>>>(bcnt, nb, gcurL, gcurN, bbase,
                                         rowptrL, rowptrN, n);

    // 3. binA: stage bucket-sorted packed edges
    const int nA = idiv_up(emax, ACHUNK);
    binA_kernel<<<2 * nA, 256, 0, stream>>>(
        rowL, colL, eL, rowN, colN, eN, gcurL, gcurN, stagedL, stagedN, nb, nA);

    // 4. binB2: per-node count/scan -> rowptr, dinv, csr
    binB2_kernel<<<dim3(nb, 2), 256, 0, stream>>>(
        bbase, stagedL, stagedN, rowptrL, rowptrN, dinvL, dinvN, csrL, csrN, n);

    // 5. layer-1 fused gather+GEMM (+BN stats) -> h bf16
    fused_gg_kernel<128, true><<<idiv_up(n, 64), 512, 0, stream>>>(
        rowptrL, csrL, rowptrN, csrN, xb, WtL1, WtN1, dinvL, dinvN,
        cb1, h, n, bn_sum, bn_sumsq);

    // 6. BN finalize + ReLU + quant -> hb
    bnquant_kernel<<<idiv_up(n * 64, 1024), 256, 0, stream>>>(
        h, hb, bn_sum, bn_sumsq, gamma, beta, 1.0f / (float)n, n * 64);

    // 7. layer-2 fused gather+GEMM -> d_out fp32
    fused_gg_kernel<64, false><<<idiv_up(n, 64), 512, 0, stream>>>(
        rowptrL, csrL, rowptrN, csrN, hb, WtL2, WtN2, dinvL, dinvN,
        cb2, d_out, n, nullptr, nullptr);
}